// Round 6
// baseline (1534.987 us; speedup 1.0000x reference)
//
#include <hip/hip_runtime.h>
#include <hip/hip_fp16.h>

#define NN 100000
#define NE 1600000
#define DIM 128
#define NGRAPH 128
#define FCD 64

#define NBK 391          // buckets of 256 target nodes: (NN+255)>>8
#define ECH 8192         // edges per pass-A chunk
#define NCH 196          // (NE + ECH - 1) / ECH
#define ECAP 8192        // pass-B per-bucket LDS capacity (avg ~4092, max ~4400)

typedef _Float16 half_t;
typedef _Float16 half2_t __attribute__((ext_vector_type(2)));
typedef _Float16 half4_t __attribute__((ext_vector_type(4)));

__device__ inline half2_t u2h(unsigned u) { union { unsigned u; half2_t h; } x; x.u = u; return x.h; }
__device__ inline unsigned h2u(half2_t h) { union { unsigned u; half2_t h; } x; x.h = h; return x.u; }

#if defined(__has_builtin)
#if __has_builtin(__builtin_amdgcn_fdot2)
#define HAS_FDOT2 1
#endif
#endif
#ifndef HAS_FDOT2
#define HAS_FDOT2 0
#endif

__device__ inline float dot2(half2_t a, half2_t b, float c) {
#if HAS_FDOT2
  return __builtin_amdgcn_fdot2(a, b, c, false);
#else
  return c + (float)a[0] * (float)b[0] + (float)a[1] * (float)b[1];
#endif
}

// ---------------- CSR build: two-level counting sort ----------------
__global__ __launch_bounds__(256) void k_bucketA(const int* __restrict__ row,
                                                 const int* __restrict__ col,
                                                 int* __restrict__ staged,
                                                 int* __restrict__ offmat,
                                                 int* __restrict__ gtot) {
  __shared__ int hist[NBK];
  __shared__ int sc[512];
  __shared__ int off[NBK + 1];
  __shared__ int fill[NBK];
  int b = blockIdx.x, t = threadIdx.x;
  int e0 = b * ECH;
  int n = NE - e0; if (n > ECH) n = ECH;
  for (int j = t; j < NBK; j += 256) { hist[j] = 0; fill[j] = 0; }
  __syncthreads();
  for (int i = t; i < n; i += 256) atomicAdd(&hist[col[e0 + i] >> 8], 1);
  __syncthreads();
  sc[t] = (t < NBK) ? hist[t] : 0;
  sc[t + 256] = (t + 256 < NBK) ? hist[t + 256] : 0;
  __syncthreads();
  #pragma unroll
  for (int o = 1; o < 512; o <<= 1) {
    int a0 = (t >= o) ? sc[t - o] : 0;
    int a1 = (t + 256 >= o) ? sc[t + 256 - o] : 0;
    __syncthreads();
    sc[t] += a0; sc[t + 256] += a1;
    __syncthreads();
  }
  if (t == 0) off[0] = 0;
  for (int j = t; j < NBK; j += 256) off[j + 1] = sc[j];
  for (int j = t; j < NBK; j += 256) if (hist[j]) atomicAdd(&gtot[j], hist[j]);
  __syncthreads();
  for (int j = t; j < NBK + 1; j += 256) offmat[b * (NBK + 1) + j] = off[j];
  for (int i = t; i < n; i += 256) {
    int c = col[e0 + i], r = row[e0 + i];
    int bkt = c >> 8;
    int pos = off[bkt] + atomicAdd(&fill[bkt], 1);
    staged[e0 + pos] = (r << 8) | (c & 255);
  }
}

__global__ void k_bsum(const int* __restrict__ gtot, int* __restrict__ gbase,
                       int* __restrict__ rowptr) {
  __shared__ int sc[512];
  int t = threadIdx.x;  // 256
  sc[t] = (t < NBK) ? gtot[t] : 0;
  sc[t + 256] = (t + 256 < NBK) ? gtot[t + 256] : 0;
  __syncthreads();
  #pragma unroll
  for (int o = 1; o < 512; o <<= 1) {
    int a0 = (t >= o) ? sc[t - o] : 0;
    int a1 = (t + 256 >= o) ? sc[t + 256 - o] : 0;
    __syncthreads();
    sc[t] += a0; sc[t + 256] += a1;
    __syncthreads();
  }
  if (t == 0) { gbase[0] = 0; rowptr[NN] = NE; }
  for (int j = t; j < NBK; j += 256) gbase[j + 1] = sc[j];
}

__global__ __launch_bounds__(256) void k_csrB(const int* __restrict__ staged,
                                              const int* __restrict__ offmat,
                                              const int* __restrict__ gbase,
                                              int* __restrict__ rowptr,
                                              float* __restrict__ dinv,
                                              int* __restrict__ csrc) {
  __shared__ int pay[ECAP];
  __shared__ int csn[256];
  __shared__ int nhist[256];
  __shared__ int nscan[256];
  __shared__ int nb[256];
  __shared__ int nfill[256];
  int bkt = blockIdx.x, t = threadIdx.x;
  int gb = gbase[bkt];
  int off = 0, cnt = 0;
  if (t < NCH) {
    int base = t * (NBK + 1) + bkt;
    off = offmat[base];
    cnt = offmat[base + 1] - off;
  }
  csn[t] = cnt;
  __syncthreads();
  #pragma unroll
  for (int o = 1; o < 256; o <<= 1) {
    int a = (t >= o) ? csn[t - o] : 0;
    __syncthreads();
    csn[t] += a;
    __syncthreads();
  }
  int lb = csn[t] - cnt;
  int total = csn[255];
  if (t < NCH) {
    const int* src = staged + t * ECH + off;
    for (int i = 0; i < cnt; i++) pay[lb + i] = src[i];
  }
  nhist[t] = 0; nfill[t] = 0;
  __syncthreads();
  for (int i = t; i < total; i += 256) atomicAdd(&nhist[pay[i] & 255], 1);
  __syncthreads();
  nscan[t] = nhist[t];
  __syncthreads();
  #pragma unroll
  for (int o = 1; o < 256; o <<= 1) {
    int a = (t >= o) ? nscan[t - o] : 0;
    __syncthreads();
    nscan[t] += a;
    __syncthreads();
  }
  nb[t] = nscan[t] - nhist[t];
  int v = bkt * 256 + t;
  if (v < NN) {
    rowptr[v] = gb + nb[t];
    dinv[v] = rsqrtf((float)(nhist[t] + 1));   // +1 self loop
  }
  __syncthreads();
  for (int i = t; i < total; i += 256) {
    int p = pay[i];
    int cl = p & 255;
    int pos = nb[cl] + atomicAdd(&nfill[cl], 1);
    csrc[gb + pos] = p >> 8;
  }
}

// ---------------- x fp32 -> fp16 (layer-0 input only) ----------------
__global__ void k_cvt(const float* __restrict__ x, half_t* __restrict__ Xh) {
  int i = blockIdx.x * 256 + threadIdx.x;
  if ((size_t)i * 4 < (size_t)NN * DIM) {
    float4 v = *(const float4*)&x[(size_t)i * 4];
    half4_t h; h[0] = (half_t)v.x; h[1] = (half_t)v.y; h[2] = (half_t)v.z; h[3] = (half_t)v.w;
    *(half4_t*)&Xh[(size_t)i * 4] = h;
  }
}

// ---------------- GEMM: Bh2[s][n][16] = dinv[n] * (X W)[n][16s..16s+15], fp16 ----
// dot2 fp16 compute, fp32 accumulate. Output is SLICE-MAJOR for k_slice locality.
__global__ __launch_bounds__(256) void k_gemm(const void* __restrict__ X, int xIsHalf,
                                              const float* __restrict__ W,
                                              const float* __restrict__ dinv,
                                              half_t* __restrict__ O) {
  __shared__ unsigned Xs[32 * 68];  // [k-pair][row] half2-as-uint, stride 68
  __shared__ unsigned Ws[32 * 68];  // [k-pair][col] half2 (W[k][j], W[k+1][j])
  int bid = blockIdx.x;
  int n0 = (bid >> 1) * 64;
  int jb = (bid & 1) * 64;
  int t = threadIdx.x;
  int tx = t & 15, ty = t >> 4;
  float acc[4][4] = {};
  for (int kb = 0; kb < 128; kb += 64) {
    __syncthreads();
    if (xIsHalf) {
      const half_t* Xp = (const half_t*)X;
      int row = t >> 2, seg = t & 3;   // row 0..63, 16B segment (8 halfs) of 64-k chunk
      int n = n0 + row;
      uint4 v = make_uint4(0, 0, 0, 0);
      if (n < NN) v = *(const uint4*)&Xp[(size_t)n * DIM + kb + seg * 8];
      int kp0 = seg * 4;
      Xs[(kp0 + 0) * 68 + row] = v.x;
      Xs[(kp0 + 1) * 68 + row] = v.y;
      Xs[(kp0 + 2) * 68 + row] = v.z;
      Xs[(kp0 + 3) * 68 + row] = v.w;
    } else {
      const float* Xp = (const float*)X;
      #pragma unroll
      for (int i = 0; i < 4; i++) {
        int e = t + i * 256;       // 0..1023
        int row = e >> 4;          // node row 0..63
        int kq = (e & 15) * 4;     // k offset in chunk, 0..60
        int n = n0 + row;
        float4 v = make_float4(0.f, 0.f, 0.f, 0.f);
        if (n < NN) v = *(const float4*)&Xp[(size_t)n * DIM + kb + kq];
        half2_t p0; p0[0] = (half_t)v.x; p0[1] = (half_t)v.y;
        half2_t p1; p1[0] = (half_t)v.z; p1[1] = (half_t)v.w;
        int kp = kq >> 1;
        Xs[(kp + 0) * 68 + row] = h2u(p0);
        Xs[(kp + 1) * 68 + row] = h2u(p1);
      }
    }
    #pragma unroll
    for (int i = 0; i < 2; i++) {
      int e = t + i * 256;      // 0..511
      int kp = e >> 4;          // 0..31
      int jq = (e & 15) * 4;
      float4 a = *(const float4*)&W[(size_t)(kb + 2 * kp) * DIM + jb + jq];
      float4 b = *(const float4*)&W[(size_t)(kb + 2 * kp + 1) * DIM + jb + jq];
      half2_t p0; p0[0] = (half_t)a.x; p0[1] = (half_t)b.x;
      half2_t p1; p1[0] = (half_t)a.y; p1[1] = (half_t)b.y;
      half2_t p2; p2[0] = (half_t)a.z; p2[1] = (half_t)b.z;
      half2_t p3; p3[0] = (half_t)a.w; p3[1] = (half_t)b.w;
      *(uint4*)&Ws[kp * 68 + jq] = make_uint4(h2u(p0), h2u(p1), h2u(p2), h2u(p3));
    }
    __syncthreads();
    #pragma unroll 8
    for (int kp = 0; kp < 32; kp++) {
      uint4 au = *(const uint4*)&Xs[kp * 68 + ty * 4];
      uint4 bu = *(const uint4*)&Ws[kp * 68 + tx * 4];
      half2_t a0 = u2h(au.x), a1 = u2h(au.y), a2 = u2h(au.z), a3 = u2h(au.w);
      half2_t b0 = u2h(bu.x), b1 = u2h(bu.y), b2 = u2h(bu.z), b3 = u2h(bu.w);
      acc[0][0] = dot2(a0, b0, acc[0][0]); acc[0][1] = dot2(a0, b1, acc[0][1]);
      acc[0][2] = dot2(a0, b2, acc[0][2]); acc[0][3] = dot2(a0, b3, acc[0][3]);
      acc[1][0] = dot2(a1, b0, acc[1][0]); acc[1][1] = dot2(a1, b1, acc[1][1]);
      acc[1][2] = dot2(a1, b2, acc[1][2]); acc[1][3] = dot2(a1, b3, acc[1][3]);
      acc[2][0] = dot2(a2, b0, acc[2][0]); acc[2][1] = dot2(a2, b1, acc[2][1]);
      acc[2][2] = dot2(a2, b2, acc[2][2]); acc[2][3] = dot2(a2, b3, acc[2][3]);
      acc[3][0] = dot2(a3, b0, acc[3][0]); acc[3][1] = dot2(a3, b1, acc[3][1]);
      acc[3][2] = dot2(a3, b2, acc[3][2]); acc[3][3] = dot2(a3, b3, acc[3][3]);
    }
  }
  int sl = (jb >> 4) + (tx >> 2);   // slice 0..7
  int fo = (tx & 3) * 4;            // feature offset within slice
  #pragma unroll
  for (int r = 0; r < 4; r++) {
    int n = n0 + ty * 4 + r;
    if (n < NN) {
      float dv = dinv[n];
      half4_t h;
      h[0] = (half_t)(acc[r][0] * dv);
      h[1] = (half_t)(acc[r][1] * dv);
      h[2] = (half_t)(acc[r][2] * dv);
      h[3] = (half_t)(acc[r][3] * dv);
      *(half4_t*)&O[((size_t)sl * NN + n) * 16 + fo] = h;
    }
  }
}

// ---------------- Sliced aggregation: S[v][16s..] = dinv[v]*(sum_u Bh2[s][u] + Bh2[s][v]) --
// grid (3125, 8): y = slice (temporal phasing -> 3.2MB slice table L2-resident).
// wave = 8 nodes x 8 feature-lanes (half2); per-lane edge loop, 4-unrolled masked.
__global__ __launch_bounds__(256) void k_slice(const half2_t* __restrict__ Bh2,
                                               half2_t* __restrict__ S,
                                               const int* __restrict__ rowptr,
                                               const int* __restrict__ csrc,
                                               const float* __restrict__ dinv) {
  int t = threadIdx.x;
  int lane = t & 63;
  int w = t >> 6;                  // wave 0..3
  int sub = lane >> 3;             // node within wave 0..7
  int f = lane & 7;                // feature-pair within slice 0..7
  int s = blockIdx.y;              // slice 0..7
  int v = blockIdx.x * 32 + w * 8 + sub;   // 3125*32 = 100000 exact
  int s0 = rowptr[v], s1 = rowptr[v + 1];
  const half2_t* T = Bh2 + (size_t)s * (NN * 8);
  float a0, a1;
  { half2_t h = T[(size_t)v * 8 + f]; a0 = (float)h[0]; a1 = (float)h[1]; }  // self loop
  for (int r = s0; __any(r < s1); r += 4) {
    int p0 = min(r + 0, NE - 1);
    int p1 = min(r + 1, NE - 1);
    int p2 = min(r + 2, NE - 1);
    int p3 = min(r + 3, NE - 1);
    int i0 = csrc[p0];
    int i1 = csrc[p1];
    int i2 = csrc[p2];
    int i3 = csrc[p3];
    unsigned u0 = h2u(T[(size_t)i0 * 8 + f]);
    unsigned u1 = h2u(T[(size_t)i1 * 8 + f]);
    unsigned u2 = h2u(T[(size_t)i2 * 8 + f]);
    unsigned u3 = h2u(T[(size_t)i3 * 8 + f]);
    u0 = (r + 0 < s1) ? u0 : 0u;
    u1 = (r + 1 < s1) ? u1 : 0u;
    u2 = (r + 2 < s1) ? u2 : 0u;
    u3 = (r + 3 < s1) ? u3 : 0u;
    half2_t h0 = u2h(u0), h1 = u2h(u1), h2 = u2h(u2), h3 = u2h(u3);
    a0 += (float)h0[0] + (float)h1[0] + (float)h2[0] + (float)h3[0];
    a1 += (float)h0[1] + (float)h1[1] + (float)h2[1] + (float)h3[1];
  }
  float dv = dinv[v];
  half2_t o; o[0] = (half_t)(a0 * dv); o[1] = (half_t)(a1 * dv);
  S[(size_t)v * 64 + s * 8 + f] = o;
}

// ---------------- bias + LayerNorm + ReLU + residual (streaming) ----------------
// one wave per node; lane owns feature pair (2l, 2l+1). A fp32 (exact residual).
__global__ __launch_bounds__(256) void k_ln(const half2_t* __restrict__ S,
                                            float* __restrict__ A,
                                            const float* __restrict__ bias,
                                            const float* __restrict__ gamma,
                                            const float* __restrict__ beta, int res) {
  int lane = threadIdx.x & 63;
  int v = blockIdx.x * 4 + (threadIdx.x >> 6);
  if (v >= NN) return;
  half2_t hs = S[(size_t)v * 64 + lane];
  float2 b2 = *(const float2*)&bias[2 * lane];
  float f0 = (float)hs[0] + b2.x;
  float f1 = (float)hs[1] + b2.y;
  float s = f0 + f1, ss = f0 * f0 + f1 * f1;
  #pragma unroll
  for (int o = 1; o < 64; o <<= 1) { s += __shfl_xor(s, o); ss += __shfl_xor(ss, o); }
  float mu = s * (1.f / 128.f);
  float var = ss * (1.f / 128.f) - mu * mu;
  float rs = rsqrtf(var + 1e-5f);
  float2 g2 = *(const float2*)&gamma[2 * lane];
  float2 e2 = *(const float2*)&beta[2 * lane];
  float y0 = fmaxf((f0 - mu) * rs * g2.x + e2.x, 0.f);
  float y1 = fmaxf((f1 - mu) * rs * g2.y + e2.y, 0.f);
  float* Ap = &A[(size_t)v * DIM + 2 * lane];
  if (res) { float2 o2 = *(const float2*)Ap; y0 += o2.x; y1 += o2.y; }
  *(float2*)Ap = make_float2(y0, y1);
}

// ---------------- Global mean pool (batch is sorted, A fp32) ----------------
__global__ __launch_bounds__(128) void k_pool(const float* __restrict__ A,
                                              const int* __restrict__ batch,
                                              float* __restrict__ sums) {
  const int CH = 64;
  int b0 = blockIdx.x * CH;
  int t = threadIdx.x;  // 128
  int nmax = NN - b0; if (nmax > CH) nmax = CH;
  __shared__ int bb[CH];
  if (t < CH) bb[t] = (b0 + t < NN) ? batch[b0 + t] : -1;
  __syncthreads();
  int gfirst = bb[0], glast = bb[nmax - 1];
  if (gfirst == glast) {
    float a0 = 0.f, a1 = 0.f, a2 = 0.f, a3 = 0.f;
    int i = 0;
    for (; i + 4 <= nmax; i += 4) {
      a0 += A[(size_t)(b0 + i + 0) * DIM + t];
      a1 += A[(size_t)(b0 + i + 1) * DIM + t];
      a2 += A[(size_t)(b0 + i + 2) * DIM + t];
      a3 += A[(size_t)(b0 + i + 3) * DIM + t];
    }
    for (; i < nmax; ++i) a0 += A[(size_t)(b0 + i) * DIM + t];
    atomicAdd(&sums[gfirst * DIM + t], (a0 + a1) + (a2 + a3));
  } else {
    float acc = 0.f;
    int cur = gfirst;
    for (int i = 0; i < nmax; i++) {
      int g = bb[i];
      if (g != cur) { atomicAdd(&sums[cur * DIM + t], acc); acc = 0.f; cur = g; }
      acc += A[(size_t)(b0 + i) * DIM + t];
    }
    atomicAdd(&sums[cur * DIM + t], acc);
  }
}

__global__ void k_cnts(const int* __restrict__ batch, float* __restrict__ cnts) {
  int g = threadIdx.x;  // 128
  int lo = 0, hi = NN;
  while (lo < hi) { int mid = (lo + hi) >> 1; if (batch[mid] < g) lo = mid + 1; else hi = mid; }
  int a = lo;
  lo = 0; hi = NN;
  while (lo < hi) { int mid = (lo + hi) >> 1; if (batch[mid] < g + 1) lo = mid + 1; else hi = mid; }
  cnts[g] = (float)(lo - a);
}

// ---------------- Head ----------------
__global__ void k_head(const float* __restrict__ sums, const float* __restrict__ cnts,
                       const float* __restrict__ W1, const float* __restrict__ b1,
                       const float* __restrict__ W2, const float* __restrict__ b2,
                       float* __restrict__ out) {
  int g = blockIdx.x, t = threadIdx.x;  // 64
  __shared__ float p[128];
  float ic = 1.f / fmaxf(cnts[g], 1.f);
  p[t] = sums[g * DIM + t] * ic;
  p[t + 64] = sums[g * DIM + 64 + t] * ic;
  __syncthreads();
  float z = b1[t];
  #pragma unroll 8
  for (int k = 0; k < 128; k++) z += p[k] * W1[k * FCD + t];
  z = fmaxf(z, 0.f);
  float sv = z * W2[t];
  #pragma unroll
  for (int o = 1; o < 64; o <<= 1) sv += __shfl_xor(sv, o);
  if (t == 0) out[g] = 1.f / (1.f + expf(-(sv + b2[0])));
}

extern "C" void kernel_launch(void* const* d_in, const int* in_sizes, int n_in,
                              void* d_out, int out_size, void* d_ws, size_t ws_size,
                              hipStream_t stream) {
  (void)in_sizes; (void)n_in; (void)out_size; (void)ws_size;
  const float* x     = (const float*)d_in[0];
  const int*   ei    = (const int*)d_in[1];
  const int*   batch = (const int*)d_in[2];
  const float* W_in  = (const float*)d_in[3];
  const float* b_in  = (const float*)d_in[4];
  const float* g_in  = (const float*)d_in[5];
  const float* be_in = (const float*)d_in[6];
  const float* W_mid = (const float*)d_in[7];
  const float* b_mid = (const float*)d_in[8];
  const float* g_mid = (const float*)d_in[9];
  const float* be_mid= (const float*)d_in[10];
  const float* W_out = (const float*)d_in[11];
  const float* b_out = (const float*)d_in[12];
  const float* g_out = (const float*)d_in[13];
  const float* be_out= (const float*)d_in[14];
  const float* W1    = (const float*)d_in[15];
  const float* b1    = (const float*)d_in[16];
  const float* W2    = (const float*)d_in[17];
  const float* b2    = (const float*)d_in[18];
  float* out = (float*)d_out;

  // workspace layout (~144 MB)
  char* p = (char*)d_ws;
  auto alloc = [&](size_t bytes) {
    char* r = p;
    p += (bytes + 255) & ~(size_t)255;
    return r;
  };
  float*  A      = (float*)alloc((size_t)NN * DIM * 4);   // node features (fp32)
  half_t* Xh     = (half_t*)alloc((size_t)NN * DIM * 2);  // input x (fp16)
  half_t* Bh2    = (half_t*)alloc((size_t)NN * DIM * 2);  // slice-major GEMM out (fp16)
  half_t* S16    = (half_t*)alloc((size_t)NN * DIM * 2);  // aggregated pre-LN (fp16)
  float*  dinv   = (float*)alloc((size_t)NN * 4);
  int*    rowptr = (int*)alloc((size_t)(NN + 1) * 4);
  int*    csrc   = (int*)alloc((size_t)NE * 4);
  int*    staged = (int*)alloc((size_t)NCH * ECH * 4);
  int*    offmat = (int*)alloc((size_t)NCH * (NBK + 1) * 4);
  int*    gtot   = (int*)alloc((size_t)(NBK + 1) * 4);
  int*    gbase  = (int*)alloc((size_t)(NBK + 1) * 4);
  float*  sums   = (float*)alloc((size_t)NGRAPH * DIM * 4);
  float*  cnts   = (float*)alloc((size_t)NGRAPH * 4);

  const int* rowp = ei;        // sources
  const int* colp = ei + NE;   // targets

  hipMemsetAsync(gtot, 0, (size_t)(NBK + 1) * 4, stream);
  hipMemsetAsync(sums, 0, (size_t)NGRAPH * DIM * 4, stream);

  k_bucketA<<<NCH, 256, 0, stream>>>(rowp, colp, staged, offmat, gtot);
  k_bsum<<<1, 256, 0, stream>>>(gtot, gbase, rowptr);
  k_csrB<<<NBK, 256, 0, stream>>>(staged, offmat, gbase, rowptr, dinv, csrc);
  k_cvt<<<(NN * DIM / 4 + 255) / 256, 256, 0, stream>>>(x, Xh);

  int gemm_grid = ((NN + 63) / 64) * 2;
  for (int l = 0; l < 8; l++) {
    const float *Wl, *bl, *gl, *bel;
    if (l == 0)      { Wl = W_in;  bl = b_in;  gl = g_in;  bel = be_in;  }
    else if (l == 7) { Wl = W_out; bl = b_out; gl = g_out; bel = be_out; }
    else             { Wl = W_mid; bl = b_mid; gl = g_mid; bel = be_mid; }
    const void* in = (l == 0) ? (const void*)Xh : (const void*)A;
    int isHalf = (l == 0) ? 1 : 0;
    k_gemm<<<gemm_grid, 256, 0, stream>>>(in, isHalf, Wl, dinv, Bh2);
    k_slice<<<dim3(3125, 8), 256, 0, stream>>>((const half2_t*)Bh2, (half2_t*)S16,
                                               rowptr, csrc, dinv);
    int res = (l >= 2 && l <= 6 && (l % 2 == 0)) ? 1 : 0;
    k_ln<<<(NN + 3) / 4, 256, 0, stream>>>((const half2_t*)S16, A, bl, gl, bel, res);
  }

  k_pool<<<(NN + 63) / 64, 128, 0, stream>>>(A, batch, sums);
  k_cnts<<<1, 128, 0, stream>>>(batch, cnts);
  k_head<<<NGRAPH, 64, 0, stream>>>(sums, cnts, W1, b1, W2, b2, out);
}

// Round 8
// 1018.279 us; speedup vs baseline: 1.5074x; 1.5074x over previous
//
#include <hip/hip_runtime.h>
#include <hip/hip_fp16.h>

#define NN 100000
#define NE 1600000
#define DIM 128
#define NGRAPH 128
#define FCD 64

#define NBK 391          // buckets of 256 target nodes: (NN+255)>>8
#define ECH 8192         // edges per pass-A chunk
#define NCH 196          // (NE + ECH - 1) / ECH
#define ECAP 8192        // pass-B per-bucket LDS capacity (avg ~4092, max ~4400)

typedef _Float16 half_t;
typedef _Float16 half2_t __attribute__((ext_vector_type(2)));
typedef _Float16 half4_t __attribute__((ext_vector_type(4)));

__device__ inline half2_t u2h(unsigned u) { union { unsigned u; half2_t h; } x; x.u = u; return x.h; }
__device__ inline unsigned h2u(half2_t h) { union { unsigned u; half2_t h; } x; x.h = h; return x.u; }

#if defined(__has_builtin)
#if __has_builtin(__builtin_amdgcn_fdot2)
#define HAS_FDOT2 1
#endif
#endif
#ifndef HAS_FDOT2
#define HAS_FDOT2 0
#endif

__device__ inline float dot2(half2_t a, half2_t b, float c) {
#if HAS_FDOT2
  return __builtin_amdgcn_fdot2(a, b, c, false);
#else
  return c + (float)a[0] * (float)b[0] + (float)a[1] * (float)b[1];
#endif
}

// ---------------- CSR build: two-level counting sort ----------------
__global__ __launch_bounds__(256) void k_bucketA(const int* __restrict__ row,
                                                 const int* __restrict__ col,
                                                 int* __restrict__ staged,
                                                 int* __restrict__ offmat,
                                                 int* __restrict__ gtot) {
  __shared__ int hist[NBK];
  __shared__ int sc[512];
  __shared__ int off[NBK + 1];
  __shared__ int fill[NBK];
  int b = blockIdx.x, t = threadIdx.x;
  int e0 = b * ECH;
  int n = NE - e0; if (n > ECH) n = ECH;
  for (int j = t; j < NBK; j += 256) { hist[j] = 0; fill[j] = 0; }
  __syncthreads();
  for (int i = t; i < n; i += 256) atomicAdd(&hist[col[e0 + i] >> 8], 1);
  __syncthreads();
  sc[t] = (t < NBK) ? hist[t] : 0;
  sc[t + 256] = (t + 256 < NBK) ? hist[t + 256] : 0;
  __syncthreads();
  #pragma unroll
  for (int o = 1; o < 512; o <<= 1) {
    int a0 = (t >= o) ? sc[t - o] : 0;
    int a1 = (t + 256 >= o) ? sc[t + 256 - o] : 0;
    __syncthreads();
    sc[t] += a0; sc[t + 256] += a1;
    __syncthreads();
  }
  if (t == 0) off[0] = 0;
  for (int j = t; j < NBK; j += 256) off[j + 1] = sc[j];
  for (int j = t; j < NBK; j += 256) if (hist[j]) atomicAdd(&gtot[j], hist[j]);
  __syncthreads();
  for (int j = t; j < NBK + 1; j += 256) offmat[b * (NBK + 1) + j] = off[j];
  for (int i = t; i < n; i += 256) {
    int c = col[e0 + i], r = row[e0 + i];
    int bkt = c >> 8;
    int pos = off[bkt] + atomicAdd(&fill[bkt], 1);
    staged[e0 + pos] = (r << 8) | (c & 255);
  }
}

__global__ void k_bsum(const int* __restrict__ gtot, int* __restrict__ gbase,
                       int* __restrict__ rowptr) {
  __shared__ int sc[512];
  int t = threadIdx.x;  // 256
  sc[t] = (t < NBK) ? gtot[t] : 0;
  sc[t + 256] = (t + 256 < NBK) ? gtot[t + 256] : 0;
  __syncthreads();
  #pragma unroll
  for (int o = 1; o < 512; o <<= 1) {
    int a0 = (t >= o) ? sc[t - o] : 0;
    int a1 = (t + 256 >= o) ? sc[t + 256 - o] : 0;
    __syncthreads();
    sc[t] += a0; sc[t + 256] += a1;
    __syncthreads();
  }
  if (t == 0) { gbase[0] = 0; rowptr[NN] = NE; }
  for (int j = t; j < NBK; j += 256) gbase[j + 1] = sc[j];
}

__global__ __launch_bounds__(256) void k_csrB(const int* __restrict__ staged,
                                              const int* __restrict__ offmat,
                                              const int* __restrict__ gbase,
                                              int* __restrict__ rowptr,
                                              float* __restrict__ dinv,
                                              int* __restrict__ csrc) {
  __shared__ int pay[ECAP];
  __shared__ int csn[256];
  __shared__ int nhist[256];
  __shared__ int nscan[256];
  __shared__ int nb[256];
  __shared__ int nfill[256];
  int bkt = blockIdx.x, t = threadIdx.x;
  int gb = gbase[bkt];
  int off = 0, cnt = 0;
  if (t < NCH) {
    int base = t * (NBK + 1) + bkt;
    off = offmat[base];
    cnt = offmat[base + 1] - off;
  }
  csn[t] = cnt;
  __syncthreads();
  #pragma unroll
  for (int o = 1; o < 256; o <<= 1) {
    int a = (t >= o) ? csn[t - o] : 0;
    __syncthreads();
    csn[t] += a;
    __syncthreads();
  }
  int lb = csn[t] - cnt;
  int total = csn[255];
  if (t < NCH) {
    const int* src = staged + t * ECH + off;
    for (int i = 0; i < cnt; i++) pay[lb + i] = src[i];
  }
  nhist[t] = 0; nfill[t] = 0;
  __syncthreads();
  for (int i = t; i < total; i += 256) atomicAdd(&nhist[pay[i] & 255], 1);
  __syncthreads();
  nscan[t] = nhist[t];
  __syncthreads();
  #pragma unroll
  for (int o = 1; o < 256; o <<= 1) {
    int a = (t >= o) ? nscan[t - o] : 0;
    __syncthreads();
    nscan[t] += a;
    __syncthreads();
  }
  nb[t] = nscan[t] - nhist[t];
  int v = bkt * 256 + t;
  if (v < NN) {
    rowptr[v] = gb + nb[t];
    dinv[v] = rsqrtf((float)(nhist[t] + 1));   // +1 self loop
  }
  __syncthreads();
  for (int i = t; i < total; i += 256) {
    int p = pay[i];
    int cl = p & 255;
    int pos = nb[cl] + atomicAdd(&nfill[cl], 1);
    csrc[gb + pos] = p >> 8;
  }
}

// ---------------- x fp32 -> fp16 (layer-0 input only) ----------------
__global__ void k_cvt(const float* __restrict__ x, half_t* __restrict__ Xh) {
  int i = blockIdx.x * 256 + threadIdx.x;
  if ((size_t)i * 4 < (size_t)NN * DIM) {
    float4 v = *(const float4*)&x[(size_t)i * 4];
    half4_t h; h[0] = (half_t)v.x; h[1] = (half_t)v.y; h[2] = (half_t)v.z; h[3] = (half_t)v.w;
    *(half4_t*)&Xh[(size_t)i * 4] = h;
  }
}

// ---------------- GEMM: O[n][j] = dinv[n] * sum_k X[n][k] * W[k][j], fp16 in/out --
// dot2 fp16 compute, fp32 accumulate. X fp16 row-major.
// Staging: 512 uint4 loads (2/thread) = full 64x64-half chunk (kp 0..31).
__global__ __launch_bounds__(256) void k_gemm(const half_t* __restrict__ X,
                                              const float* __restrict__ W,
                                              const float* __restrict__ dinv,
                                              half_t* __restrict__ O) {
  __shared__ unsigned Xs[32 * 68];  // [k-pair][row] half2-as-uint, stride 68
  __shared__ unsigned Ws[32 * 68];  // [k-pair][col] half2 (W[k][j], W[k+1][j])
  int bid = blockIdx.x;
  int n0 = (bid >> 1) * 64;
  int jb = (bid & 1) * 64;
  int t = threadIdx.x;
  int tx = t & 15, ty = t >> 4;
  float acc[4][4] = {};
  for (int kb = 0; kb < 128; kb += 64) {
    __syncthreads();
    #pragma unroll
    for (int i = 0; i < 2; i++) {
      int e = t + i * 256;             // 0..511
      int row = e >> 3;                // node row 0..63
      int seg = e & 7;                 // 8 segments x 8 halfs = full 64-half chunk
      int n = n0 + row;
      uint4 v = make_uint4(0, 0, 0, 0);
      if (n < NN) v = *(const uint4*)&X[(size_t)n * DIM + kb + seg * 8];
      int kp0 = seg * 4;               // k-pair 0..28
      Xs[(kp0 + 0) * 68 + row] = v.x;
      Xs[(kp0 + 1) * 68 + row] = v.y;
      Xs[(kp0 + 2) * 68 + row] = v.z;
      Xs[(kp0 + 3) * 68 + row] = v.w;
    }
    #pragma unroll
    for (int i = 0; i < 2; i++) {
      int e = t + i * 256;      // 0..511
      int kp = e >> 4;          // 0..31
      int jq = (e & 15) * 4;
      float4 a = *(const float4*)&W[(size_t)(kb + 2 * kp) * DIM + jb + jq];
      float4 b = *(const float4*)&W[(size_t)(kb + 2 * kp + 1) * DIM + jb + jq];
      half2_t p0; p0[0] = (half_t)a.x; p0[1] = (half_t)b.x;
      half2_t p1; p1[0] = (half_t)a.y; p1[1] = (half_t)b.y;
      half2_t p2; p2[0] = (half_t)a.z; p2[1] = (half_t)b.z;
      half2_t p3; p3[0] = (half_t)a.w; p3[1] = (half_t)b.w;
      *(uint4*)&Ws[kp * 68 + jq] = make_uint4(h2u(p0), h2u(p1), h2u(p2), h2u(p3));
    }
    __syncthreads();
    #pragma unroll 8
    for (int kp = 0; kp < 32; kp++) {
      uint4 au = *(const uint4*)&Xs[kp * 68 + ty * 4];
      uint4 bu = *(const uint4*)&Ws[kp * 68 + tx * 4];
      half2_t a0 = u2h(au.x), a1 = u2h(au.y), a2 = u2h(au.z), a3 = u2h(au.w);
      half2_t b0 = u2h(bu.x), b1 = u2h(bu.y), b2 = u2h(bu.z), b3 = u2h(bu.w);
      acc[0][0] = dot2(a0, b0, acc[0][0]); acc[0][1] = dot2(a0, b1, acc[0][1]);
      acc[0][2] = dot2(a0, b2, acc[0][2]); acc[0][3] = dot2(a0, b3, acc[0][3]);
      acc[1][0] = dot2(a1, b0, acc[1][0]); acc[1][1] = dot2(a1, b1, acc[1][1]);
      acc[1][2] = dot2(a1, b2, acc[1][2]); acc[1][3] = dot2(a1, b3, acc[1][3]);
      acc[2][0] = dot2(a2, b0, acc[2][0]); acc[2][1] = dot2(a2, b1, acc[2][1]);
      acc[2][2] = dot2(a2, b2, acc[2][2]); acc[2][3] = dot2(a2, b3, acc[2][3]);
      acc[3][0] = dot2(a3, b0, acc[3][0]); acc[3][1] = dot2(a3, b1, acc[3][1]);
      acc[3][2] = dot2(a3, b2, acc[3][2]); acc[3][3] = dot2(a3, b3, acc[3][3]);
    }
  }
  #pragma unroll
  for (int r = 0; r < 4; r++) {
    int n = n0 + ty * 4 + r;
    if (n < NN) {
      float dv = dinv[n];
      half4_t h;
      h[0] = (half_t)(acc[r][0] * dv);
      h[1] = (half_t)(acc[r][1] * dv);
      h[2] = (half_t)(acc[r][2] * dv);
      h[3] = (half_t)(acc[r][3] * dv);
      *(half4_t*)&O[(size_t)n * DIM + jb + tx * 4] = h;
    }
  }
}

// ---------------- Aggregation + bias + LayerNorm + ReLU + residual ----------------
// one wave per node; lane owns feature pair (2l, 2l+1). A fp32 (exact residual);
// Ah is the fp16 copy of the final value, feeding the next layer's GEMM.
__global__ __launch_bounds__(256) void k_agg(const half2_t* __restrict__ Hh,
                      float* __restrict__ A, half2_t* __restrict__ Ah,
                      const int* __restrict__ rowptr, const int* __restrict__ csrc,
                      const float* __restrict__ dinv,
                      const float* __restrict__ bias, const float* __restrict__ gamma,
                      const float* __restrict__ beta, int res) {
  int lane = threadIdx.x & 63;
  int v = blockIdx.x * 4 + (threadIdx.x >> 6);
  if (v >= NN) return;
  int s0 = rowptr[v], s1 = rowptr[v + 1];
  half2_t hs = Hh[(size_t)v * 64 + lane];          // self-loop term
  float a0 = (float)hs[0], a1 = (float)hs[1];
  int i = s0;
  int head = (s0 + 3) & ~3;
  if (head > s1) head = s1;
  for (; i < head; ++i) {                          // peel to int4 alignment
    half2_t h = Hh[(size_t)csrc[i] * 64 + lane];
    a0 += (float)h[0]; a1 += (float)h[1];
  }
  for (; i + 8 <= s1; i += 8) {                    // 8 gathers in flight
    int4 sa = *(const int4*)&csrc[i];
    int4 sb = *(const int4*)&csrc[i + 4];
    half2_t h0 = Hh[(size_t)sa.x * 64 + lane];
    half2_t h1 = Hh[(size_t)sa.y * 64 + lane];
    half2_t h2 = Hh[(size_t)sa.z * 64 + lane];
    half2_t h3 = Hh[(size_t)sa.w * 64 + lane];
    half2_t h4 = Hh[(size_t)sb.x * 64 + lane];
    half2_t h5 = Hh[(size_t)sb.y * 64 + lane];
    half2_t h6 = Hh[(size_t)sb.z * 64 + lane];
    half2_t h7 = Hh[(size_t)sb.w * 64 + lane];
    a0 += ((float)h0[0] + (float)h1[0]) + ((float)h2[0] + (float)h3[0])
        + ((float)h4[0] + (float)h5[0]) + ((float)h6[0] + (float)h7[0]);
    a1 += ((float)h0[1] + (float)h1[1]) + ((float)h2[1] + (float)h3[1])
        + ((float)h4[1] + (float)h5[1]) + ((float)h6[1] + (float)h7[1]);
  }
  if (i + 4 <= s1) {
    int4 s4 = *(const int4*)&csrc[i];
    half2_t h0 = Hh[(size_t)s4.x * 64 + lane];
    half2_t h1 = Hh[(size_t)s4.y * 64 + lane];
    half2_t h2 = Hh[(size_t)s4.z * 64 + lane];
    half2_t h3 = Hh[(size_t)s4.w * 64 + lane];
    a0 += (float)h0[0] + (float)h1[0] + (float)h2[0] + (float)h3[0];
    a1 += (float)h0[1] + (float)h1[1] + (float)h2[1] + (float)h3[1];
    i += 4;
  }
  for (; i < s1; ++i) {
    half2_t h = Hh[(size_t)csrc[i] * 64 + lane];
    a0 += (float)h[0]; a1 += (float)h[1];
  }
  float dv = dinv[v];
  float2 b2 = *(const float2*)&bias[2 * lane];
  float f0 = a0 * dv + b2.x;
  float f1 = a1 * dv + b2.y;
  float s = f0 + f1, ss = f0 * f0 + f1 * f1;
  #pragma unroll
  for (int o = 1; o < 64; o <<= 1) { s += __shfl_xor(s, o); ss += __shfl_xor(ss, o); }
  float mu = s * (1.f / 128.f);
  float var = ss * (1.f / 128.f) - mu * mu;
  float rs = rsqrtf(var + 1e-5f);
  float2 g2 = *(const float2*)&gamma[2 * lane];
  float2 e2 = *(const float2*)&beta[2 * lane];
  float y0 = fmaxf((f0 - mu) * rs * g2.x + e2.x, 0.f);
  float y1 = fmaxf((f1 - mu) * rs * g2.y + e2.y, 0.f);
  float* Ap = &A[(size_t)v * DIM + 2 * lane];
  if (res) { float2 o2 = *(const float2*)Ap; y0 += o2.x; y1 += o2.y; }
  *(float2*)Ap = make_float2(y0, y1);
  half2_t w; w[0] = (half_t)y0; w[1] = (half_t)y1;
  Ah[(size_t)v * 64 + lane] = w;
}

// ---------------- Global mean pool (batch is sorted, A fp32) ----------------
__global__ __launch_bounds__(128) void k_pool(const float* __restrict__ A,
                                              const int* __restrict__ batch,
                                              float* __restrict__ sums) {
  const int CH = 64;
  int b0 = blockIdx.x * CH;
  int t = threadIdx.x;  // 128
  int nmax = NN - b0; if (nmax > CH) nmax = CH;
  __shared__ int bb[CH];
  if (t < CH) bb[t] = (b0 + t < NN) ? batch[b0 + t] : -1;
  __syncthreads();
  int gfirst = bb[0], glast = bb[nmax - 1];
  if (gfirst == glast) {
    float a0 = 0.f, a1 = 0.f, a2 = 0.f, a3 = 0.f;
    int i = 0;
    for (; i + 4 <= nmax; i += 4) {
      a0 += A[(size_t)(b0 + i + 0) * DIM + t];
      a1 += A[(size_t)(b0 + i + 1) * DIM + t];
      a2 += A[(size_t)(b0 + i + 2) * DIM + t];
      a3 += A[(size_t)(b0 + i + 3) * DIM + t];
    }
    for (; i < nmax; ++i) a0 += A[(size_t)(b0 + i) * DIM + t];
    atomicAdd(&sums[gfirst * DIM + t], (a0 + a1) + (a2 + a3));
  } else {
    float acc = 0.f;
    int cur = gfirst;
    for (int i = 0; i < nmax; i++) {
      int g = bb[i];
      if (g != cur) { atomicAdd(&sums[cur * DIM + t], acc); acc = 0.f; cur = g; }
      acc += A[(size_t)(b0 + i) * DIM + t];
    }
    atomicAdd(&sums[cur * DIM + t], acc);
  }
}

__global__ void k_cnts(const int* __restrict__ batch, float* __restrict__ cnts) {
  int g = threadIdx.x;  // 128
  int lo = 0, hi = NN;
  while (lo < hi) { int mid = (lo + hi) >> 1; if (batch[mid] < g) lo = mid + 1; else hi = mid; }
  int a = lo;
  lo = 0; hi = NN;
  while (lo < hi) { int mid = (lo + hi) >> 1; if (batch[mid] < g + 1) lo = mid + 1; else hi = mid; }
  cnts[g] = (float)(lo - a);
}

// ---------------- Head ----------------
__global__ void k_head(const float* __restrict__ sums, const float* __restrict__ cnts,
                       const float* __restrict__ W1, const float* __restrict__ b1,
                       const float* __restrict__ W2, const float* __restrict__ b2,
                       float* __restrict__ out) {
  int g = blockIdx.x, t = threadIdx.x;  // 64
  __shared__ float p[128];
  float ic = 1.f / fmaxf(cnts[g], 1.f);
  p[t] = sums[g * DIM + t] * ic;
  p[t + 64] = sums[g * DIM + 64 + t] * ic;
  __syncthreads();
  float z = b1[t];
  #pragma unroll 8
  for (int k = 0; k < 128; k++) z += p[k] * W1[k * FCD + t];
  z = fmaxf(z, 0.f);
  float sv = z * W2[t];
  #pragma unroll
  for (int o = 1; o < 64; o <<= 1) sv += __shfl_xor(sv, o);
  if (t == 0) out[g] = 1.f / (1.f + expf(-(sv + b2[0])));
}

extern "C" void kernel_launch(void* const* d_in, const int* in_sizes, int n_in,
                              void* d_out, int out_size, void* d_ws, size_t ws_size,
                              hipStream_t stream) {
  (void)in_sizes; (void)n_in; (void)out_size; (void)ws_size;
  const float* x     = (const float*)d_in[0];
  const int*   ei    = (const int*)d_in[1];
  const int*   batch = (const int*)d_in[2];
  const float* W_in  = (const float*)d_in[3];
  const float* b_in  = (const float*)d_in[4];
  const float* g_in  = (const float*)d_in[5];
  const float* be_in = (const float*)d_in[6];
  const float* W_mid = (const float*)d_in[7];
  const float* b_mid = (const float*)d_in[8];
  const float* g_mid = (const float*)d_in[9];
  const float* be_mid= (const float*)d_in[10];
  const float* W_out = (const float*)d_in[11];
  const float* b_out = (const float*)d_in[12];
  const float* g_out = (const float*)d_in[13];
  const float* be_out= (const float*)d_in[14];
  const float* W1    = (const float*)d_in[15];
  const float* b1    = (const float*)d_in[16];
  const float* W2    = (const float*)d_in[17];
  const float* b2    = (const float*)d_in[18];
  float* out = (float*)d_out;

  // workspace layout (~144 MB)
  char* p = (char*)d_ws;
  auto alloc = [&](size_t bytes) {
    char* r = p;
    p += (bytes + 255) & ~(size_t)255;
    return r;
  };
  float*  A      = (float*)alloc((size_t)NN * DIM * 4);   // node features (fp32, exact)
  half_t* Ah     = (half_t*)alloc((size_t)NN * DIM * 2);  // fp16 copy for next GEMM
  half_t* Xh     = (half_t*)alloc((size_t)NN * DIM * 2);  // input x (fp16)
  half_t* Bh     = (half_t*)alloc((size_t)NN * DIM * 2);  // scaled linear output (fp16)
  float*  dinv   = (float*)alloc((size_t)NN * 4);
  int*    rowptr = (int*)alloc((size_t)(NN + 1) * 4);
  int*    csrc   = (int*)alloc((size_t)NE * 4);
  int*    staged = (int*)alloc((size_t)NCH * ECH * 4);
  int*    offmat = (int*)alloc((size_t)NCH * (NBK + 1) * 4);
  int*    gtot   = (int*)alloc((size_t)(NBK + 1) * 4);
  int*    gbase  = (int*)alloc((size_t)(NBK + 1) * 4);
  float*  sums   = (float*)alloc((size_t)NGRAPH * DIM * 4);
  float*  cnts   = (float*)alloc((size_t)NGRAPH * 4);

  const int* rowp = ei;        // sources
  const int* colp = ei + NE;   // targets

  hipMemsetAsync(gtot, 0, (size_t)(NBK + 1) * 4, stream);
  hipMemsetAsync(sums, 0, (size_t)NGRAPH * DIM * 4, stream);

  k_bucketA<<<NCH, 256, 0, stream>>>(rowp, colp, staged, offmat, gtot);
  k_bsum<<<1, 256, 0, stream>>>(gtot, gbase, rowptr);
  k_csrB<<<NBK, 256, 0, stream>>>(staged, offmat, gbase, rowptr, dinv, csrc);
  k_cvt<<<(NN * DIM / 4 + 255) / 256, 256, 0, stream>>>(x, Xh);

  int gemm_grid = ((NN + 63) / 64) * 2;
  for (int l = 0; l < 8; l++) {
    const float *Wl, *bl, *gl, *bel;
    if (l == 0)      { Wl = W_in;  bl = b_in;  gl = g_in;  bel = be_in;  }
    else if (l == 7) { Wl = W_out; bl = b_out; gl = g_out; bel = be_out; }
    else             { Wl = W_mid; bl = b_mid; gl = g_mid; bel = be_mid; }
    const half_t* in = (l == 0) ? Xh : Ah;
    k_gemm<<<gemm_grid, 256, 0, stream>>>(in, Wl, dinv, Bh);
    int res = (l >= 2 && l <= 6 && (l % 2 == 0)) ? 1 : 0;
    k_agg<<<(NN + 3) / 4, 256, 0, stream>>>((const half2_t*)Bh, A, (half2_t*)Ah,
                                            rowptr, csrc, dinv, bl, gl, bel, res);
  }

  k_pool<<<(NN + 63) / 64, 128, 0, stream>>>(A, batch, sums);
  k_cnts<<<1, 128, 0, stream>>>(batch, cnts);
  k_head<<<NGRAPH, 64, 0, stream>>>(sums, cnts, W1, b1, W2, b2, out);
}

// Round 9
// 990.155 us; speedup vs baseline: 1.5502x; 1.0284x over previous
//
#include <hip/hip_runtime.h>
#include <hip/hip_fp16.h>

#define NN 100000
#define NE 1600000
#define DIM 128
#define NGRAPH 128
#define FCD 64

#define NBK 391          // buckets of 256 target nodes: (NN+255)>>8
#define ECH 8192         // edges per pass-A chunk
#define NCH 196          // (NE + ECH - 1) / ECH
#define ECAP 8192        // pass-B per-bucket LDS capacity (avg ~4092, max ~4400)

typedef _Float16 half_t;
typedef _Float16 half2_t __attribute__((ext_vector_type(2)));
typedef _Float16 half4_t __attribute__((ext_vector_type(4)));

__device__ inline half2_t u2h(unsigned u) { union { unsigned u; half2_t h; } x; x.u = u; return x.h; }
__device__ inline unsigned h2u(half2_t h) { union { unsigned u; half2_t h; } x; x.h = h; return x.u; }

#if defined(__has_builtin)
#if __has_builtin(__builtin_amdgcn_fdot2)
#define HAS_FDOT2 1
#endif
#endif
#ifndef HAS_FDOT2
#define HAS_FDOT2 0
#endif

__device__ inline float dot2(half2_t a, half2_t b, float c) {
#if HAS_FDOT2
  return __builtin_amdgcn_fdot2(a, b, c, false);
#else
  return c + (float)a[0] * (float)b[0] + (float)a[1] * (float)b[1];
#endif
}

// ---------------- CSR build: two-level counting sort ----------------
__global__ __launch_bounds__(256) void k_bucketA(const int* __restrict__ row,
                                                 const int* __restrict__ col,
                                                 int* __restrict__ staged,
                                                 int* __restrict__ offmat,
                                                 int* __restrict__ gtot) {
  __shared__ int hist[NBK];
  __shared__ int sc[512];
  __shared__ int off[NBK + 1];
  __shared__ int fill[NBK];
  int b = blockIdx.x, t = threadIdx.x;
  int e0 = b * ECH;
  int n = NE - e0; if (n > ECH) n = ECH;
  for (int j = t; j < NBK; j += 256) { hist[j] = 0; fill[j] = 0; }
  __syncthreads();
  for (int i = t; i < n; i += 256) atomicAdd(&hist[col[e0 + i] >> 8], 1);
  __syncthreads();
  sc[t] = (t < NBK) ? hist[t] : 0;
  sc[t + 256] = (t + 256 < NBK) ? hist[t + 256] : 0;
  __syncthreads();
  #pragma unroll
  for (int o = 1; o < 512; o <<= 1) {
    int a0 = (t >= o) ? sc[t - o] : 0;
    int a1 = (t + 256 >= o) ? sc[t + 256 - o] : 0;
    __syncthreads();
    sc[t] += a0; sc[t + 256] += a1;
    __syncthreads();
  }
  if (t == 0) off[0] = 0;
  for (int j = t; j < NBK; j += 256) off[j + 1] = sc[j];
  for (int j = t; j < NBK; j += 256) if (hist[j]) atomicAdd(&gtot[j], hist[j]);
  __syncthreads();
  for (int j = t; j < NBK + 1; j += 256) offmat[b * (NBK + 1) + j] = off[j];
  for (int i = t; i < n; i += 256) {
    int c = col[e0 + i], r = row[e0 + i];
    int bkt = c >> 8;
    int pos = off[bkt] + atomicAdd(&fill[bkt], 1);
    staged[e0 + pos] = (r << 8) | (c & 255);
  }
}

__global__ void k_bsum(const int* __restrict__ gtot, int* __restrict__ gbase,
                       int* __restrict__ rowptr) {
  __shared__ int sc[512];
  int t = threadIdx.x;  // 256
  sc[t] = (t < NBK) ? gtot[t] : 0;
  sc[t + 256] = (t + 256 < NBK) ? gtot[t + 256] : 0;
  __syncthreads();
  #pragma unroll
  for (int o = 1; o < 512; o <<= 1) {
    int a0 = (t >= o) ? sc[t - o] : 0;
    int a1 = (t + 256 >= o) ? sc[t + 256 - o] : 0;
    __syncthreads();
    sc[t] += a0; sc[t + 256] += a1;
    __syncthreads();
  }
  if (t == 0) { gbase[0] = 0; rowptr[NN] = NE; }
  for (int j = t; j < NBK; j += 256) gbase[j + 1] = sc[j];
}

__global__ __launch_bounds__(256) void k_csrB(const int* __restrict__ staged,
                                              const int* __restrict__ offmat,
                                              const int* __restrict__ gbase,
                                              int* __restrict__ rowptr,
                                              float* __restrict__ dinv,
                                              int* __restrict__ csrc) {
  __shared__ int pay[ECAP];
  __shared__ int csn[256];
  __shared__ int nhist[256];
  __shared__ int nscan[256];
  __shared__ int nb[256];
  __shared__ int nfill[256];
  int bkt = blockIdx.x, t = threadIdx.x;
  int gb = gbase[bkt];
  int off = 0, cnt = 0;
  if (t < NCH) {
    int base = t * (NBK + 1) + bkt;
    off = offmat[base];
    cnt = offmat[base + 1] - off;
  }
  csn[t] = cnt;
  __syncthreads();
  #pragma unroll
  for (int o = 1; o < 256; o <<= 1) {
    int a = (t >= o) ? csn[t - o] : 0;
    __syncthreads();
    csn[t] += a;
    __syncthreads();
  }
  int lb = csn[t] - cnt;
  int total = csn[255];
  if (t < NCH) {
    const int* src = staged + t * ECH + off;
    for (int i = 0; i < cnt; i++) pay[lb + i] = src[i];
  }
  nhist[t] = 0; nfill[t] = 0;
  __syncthreads();
  for (int i = t; i < total; i += 256) atomicAdd(&nhist[pay[i] & 255], 1);
  __syncthreads();
  nscan[t] = nhist[t];
  __syncthreads();
  #pragma unroll
  for (int o = 1; o < 256; o <<= 1) {
    int a = (t >= o) ? nscan[t - o] : 0;
    __syncthreads();
    nscan[t] += a;
    __syncthreads();
  }
  nb[t] = nscan[t] - nhist[t];
  int v = bkt * 256 + t;
  if (v < NN) {
    rowptr[v] = gb + nb[t];
    dinv[v] = rsqrtf((float)(nhist[t] + 1));   // +1 self loop
  }
  __syncthreads();
  for (int i = t; i < total; i += 256) {
    int p = pay[i];
    int cl = p & 255;
    int pos = nb[cl] + atomicAdd(&nfill[cl], 1);
    csrc[gb + pos] = p >> 8;
  }
}

// ---------------- x fp32 -> fp16 (layer-0 input only) ----------------
__global__ void k_cvt(const float* __restrict__ x, half_t* __restrict__ Xh) {
  int i = blockIdx.x * 256 + threadIdx.x;
  if ((size_t)i * 4 < (size_t)NN * DIM) {
    float4 v = *(const float4*)&x[(size_t)i * 4];
    half4_t h; h[0] = (half_t)v.x; h[1] = (half_t)v.y; h[2] = (half_t)v.z; h[3] = (half_t)v.w;
    *(half4_t*)&Xh[(size_t)i * 4] = h;
  }
}

// ---------------- GEMM: O[n][j] = dinv[n] * sum_k X[n][k] * W[k][j], fp16 in/out --
__global__ __launch_bounds__(256) void k_gemm(const half_t* __restrict__ X,
                                              const float* __restrict__ W,
                                              const float* __restrict__ dinv,
                                              half_t* __restrict__ O) {
  __shared__ unsigned Xs[32 * 68];  // [k-pair][row] half2-as-uint, stride 68
  __shared__ unsigned Ws[32 * 68];  // [k-pair][col] half2 (W[k][j], W[k+1][j])
  int bid = blockIdx.x;
  int n0 = (bid >> 1) * 64;
  int jb = (bid & 1) * 64;
  int t = threadIdx.x;
  int tx = t & 15, ty = t >> 4;
  float acc[4][4] = {};
  for (int kb = 0; kb < 128; kb += 64) {
    __syncthreads();
    #pragma unroll
    for (int i = 0; i < 2; i++) {
      int e = t + i * 256;             // 0..511
      int row = e >> 3;                // node row 0..63
      int seg = e & 7;                 // 8 segments x 8 halfs = full 64-half chunk
      int n = n0 + row;
      uint4 v = make_uint4(0, 0, 0, 0);
      if (n < NN) v = *(const uint4*)&X[(size_t)n * DIM + kb + seg * 8];
      int kp0 = seg * 4;               // k-pair 0..28
      Xs[(kp0 + 0) * 68 + row] = v.x;
      Xs[(kp0 + 1) * 68 + row] = v.y;
      Xs[(kp0 + 2) * 68 + row] = v.z;
      Xs[(kp0 + 3) * 68 + row] = v.w;
    }
    #pragma unroll
    for (int i = 0; i < 2; i++) {
      int e = t + i * 256;      // 0..511
      int kp = e >> 4;          // 0..31
      int jq = (e & 15) * 4;
      float4 a = *(const float4*)&W[(size_t)(kb + 2 * kp) * DIM + jb + jq];
      float4 b = *(const float4*)&W[(size_t)(kb + 2 * kp + 1) * DIM + jb + jq];
      half2_t p0; p0[0] = (half_t)a.x; p0[1] = (half_t)b.x;
      half2_t p1; p1[0] = (half_t)a.y; p1[1] = (half_t)b.y;
      half2_t p2; p2[0] = (half_t)a.z; p2[1] = (half_t)b.z;
      half2_t p3; p3[0] = (half_t)a.w; p3[1] = (half_t)b.w;
      *(uint4*)&Ws[kp * 68 + jq] = make_uint4(h2u(p0), h2u(p1), h2u(p2), h2u(p3));
    }
    __syncthreads();
    #pragma unroll 8
    for (int kp = 0; kp < 32; kp++) {
      uint4 au = *(const uint4*)&Xs[kp * 68 + ty * 4];
      uint4 bu = *(const uint4*)&Ws[kp * 68 + tx * 4];
      half2_t a0 = u2h(au.x), a1 = u2h(au.y), a2 = u2h(au.z), a3 = u2h(au.w);
      half2_t b0 = u2h(bu.x), b1 = u2h(bu.y), b2 = u2h(bu.z), b3 = u2h(bu.w);
      acc[0][0] = dot2(a0, b0, acc[0][0]); acc[0][1] = dot2(a0, b1, acc[0][1]);
      acc[0][2] = dot2(a0, b2, acc[0][2]); acc[0][3] = dot2(a0, b3, acc[0][3]);
      acc[1][0] = dot2(a1, b0, acc[1][0]); acc[1][1] = dot2(a1, b1, acc[1][1]);
      acc[1][2] = dot2(a1, b2, acc[1][2]); acc[1][3] = dot2(a1, b3, acc[1][3]);
      acc[2][0] = dot2(a2, b0, acc[2][0]); acc[2][1] = dot2(a2, b1, acc[2][1]);
      acc[2][2] = dot2(a2, b2, acc[2][2]); acc[2][3] = dot2(a2, b3, acc[2][3]);
      acc[3][0] = dot2(a3, b0, acc[3][0]); acc[3][1] = dot2(a3, b1, acc[3][1]);
      acc[3][2] = dot2(a3, b2, acc[3][2]); acc[3][3] = dot2(a3, b3, acc[3][3]);
    }
  }
  #pragma unroll
  for (int r = 0; r < 4; r++) {
    int n = n0 + ty * 4 + r;
    if (n < NN) {
      float dv = dinv[n];
      half4_t h;
      h[0] = (half_t)(acc[r][0] * dv);
      h[1] = (half_t)(acc[r][1] * dv);
      h[2] = (half_t)(acc[r][2] * dv);
      h[3] = (half_t)(acc[r][3] * dv);
      *(half4_t*)&O[(size_t)n * DIM + jb + tx * 4] = h;
    }
  }
}

// ---------------- Aggregation + bias + LayerNorm + ReLU + residual ----------------
// one wave per node; lane = 16-lane group g (edge phase 0..3) x feature octet fl.
// One dwordx4 load serves 4 edges (4 groups x 16 lanes x 16B = 4 rows of 256B).
// Edge sum accumulates in packed fp16 (v_pk_add_f16); self-loop/bias/LN/residual fp32.
__global__ __launch_bounds__(256) void k_agg(const half2_t* __restrict__ Hh,
                      float* __restrict__ A, half2_t* __restrict__ Ah,
                      const int* __restrict__ rowptr, const int* __restrict__ csrc,
                      const float* __restrict__ dinv,
                      const float* __restrict__ bias, const float* __restrict__ gamma,
                      const float* __restrict__ beta, int res) {
  int tid = threadIdx.x;
  int lane = tid & 63;
  int v = blockIdx.x * 4 + (tid >> 6);   // one node per wave; NN % 4 == 0
  int g = lane >> 4;                     // edge phase 0..3
  int fl = lane & 15;                    // feature octet 0..15 (8 halfs)
  int s0 = rowptr[v];
  int cnt = rowptr[v + 1] - s0;
  const uint4* Hq = (const uint4*)Hh;    // 16 uint4 per 128-half row
  half2_t a0 = u2h(0u), a1 = u2h(0u), a2 = u2h(0u), a3 = u2h(0u);
  for (int i = g; i < cnt; i += 8) {     // phases g, g+4 per iter; union covers all
    int j = i + 4;
    int jc = (j < cnt) ? j : (cnt - 1);
    int e0 = csrc[s0 + i];
    int e1 = csrc[s0 + jc];
    uint4 q0 = Hq[(size_t)e0 * 16 + fl];
    uint4 q1 = Hq[(size_t)e1 * 16 + fl];
    a0 += u2h(q0.x); a1 += u2h(q0.y); a2 += u2h(q0.z); a3 += u2h(q0.w);
    if (j < cnt) { a0 += u2h(q1.x); a1 += u2h(q1.y); a2 += u2h(q1.z); a3 += u2h(q1.w); }
  }
  // to fp32, reduce the 4 edge phases (lanes l, l^16, l^32 hold same features)
  float f0 = (float)a0[0], f1 = (float)a0[1], f2 = (float)a1[0], f3 = (float)a1[1];
  float f4 = (float)a2[0], f5 = (float)a2[1], f6 = (float)a3[0], f7 = (float)a3[1];
  f0 += __shfl_xor(f0, 16); f0 += __shfl_xor(f0, 32);
  f1 += __shfl_xor(f1, 16); f1 += __shfl_xor(f1, 32);
  f2 += __shfl_xor(f2, 16); f2 += __shfl_xor(f2, 32);
  f3 += __shfl_xor(f3, 16); f3 += __shfl_xor(f3, 32);
  f4 += __shfl_xor(f4, 16); f4 += __shfl_xor(f4, 32);
  f5 += __shfl_xor(f5, 16); f5 += __shfl_xor(f5, 32);
  f6 += __shfl_xor(f6, 16); f6 += __shfl_xor(f6, 32);
  f7 += __shfl_xor(f7, 16); f7 += __shfl_xor(f7, 32);
  // self-loop in fp32
  uint4 qs = Hq[(size_t)v * 16 + fl];
  half2_t s0h = u2h(qs.x), s1h = u2h(qs.y), s2h = u2h(qs.z), s3h = u2h(qs.w);
  f0 += (float)s0h[0]; f1 += (float)s0h[1]; f2 += (float)s1h[0]; f3 += (float)s1h[1];
  f4 += (float)s2h[0]; f5 += (float)s2h[1]; f6 += (float)s3h[0]; f7 += (float)s3h[1];
  float dv = dinv[v];
  float4 ba = *(const float4*)&bias[fl * 8];
  float4 bb = *(const float4*)&bias[fl * 8 + 4];
  f0 = f0 * dv + ba.x; f1 = f1 * dv + ba.y; f2 = f2 * dv + ba.z; f3 = f3 * dv + ba.w;
  f4 = f4 * dv + bb.x; f5 = f5 * dv + bb.y; f6 = f6 * dv + bb.z; f7 = f7 * dv + bb.w;
  // LayerNorm stats over 16 octets (values replicated across phases)
  float s  = ((f0 + f1) + (f2 + f3)) + ((f4 + f5) + (f6 + f7));
  float ss = ((f0 * f0 + f1 * f1) + (f2 * f2 + f3 * f3))
           + ((f4 * f4 + f5 * f5) + (f6 * f6 + f7 * f7));
  #pragma unroll
  for (int o = 1; o < 16; o <<= 1) { s += __shfl_xor(s, o); ss += __shfl_xor(ss, o); }
  float mu = s * (1.f / 128.f);
  float var = ss * (1.f / 128.f) - mu * mu;
  float rs = rsqrtf(var + 1e-5f);
  // phase g writes features fl*8 + 2g, 2g+1
  float pa = (g == 0) ? f0 : (g == 1) ? f2 : (g == 2) ? f4 : f6;
  float pb = (g == 0) ? f1 : (g == 1) ? f3 : (g == 2) ? f5 : f7;
  int fi = fl * 8 + g * 2;
  float2 g2 = *(const float2*)&gamma[fi];
  float2 e2 = *(const float2*)&beta[fi];
  float y0 = fmaxf((pa - mu) * rs * g2.x + e2.x, 0.f);
  float y1 = fmaxf((pb - mu) * rs * g2.y + e2.y, 0.f);
  float* Ap = &A[(size_t)v * DIM + fi];
  if (res) { float2 o2 = *(const float2*)Ap; y0 += o2.x; y1 += o2.y; }
  *(float2*)Ap = make_float2(y0, y1);
  half2_t w; w[0] = (half_t)y0; w[1] = (half_t)y1;
  Ah[(size_t)v * 64 + (fi >> 1)] = w;
}

// ---------------- Global mean pool (batch is sorted, A fp32) ----------------
__global__ __launch_bounds__(128) void k_pool(const float* __restrict__ A,
                                              const int* __restrict__ batch,
                                              float* __restrict__ sums) {
  const int CH = 64;
  int b0 = blockIdx.x * CH;
  int t = threadIdx.x;  // 128
  int nmax = NN - b0; if (nmax > CH) nmax = CH;
  __shared__ int bb[CH];
  if (t < CH) bb[t] = (b0 + t < NN) ? batch[b0 + t] : -1;
  __syncthreads();
  int gfirst = bb[0], glast = bb[nmax - 1];
  if (gfirst == glast) {
    float a0 = 0.f, a1 = 0.f, a2 = 0.f, a3 = 0.f;
    int i = 0;
    for (; i + 4 <= nmax; i += 4) {
      a0 += A[(size_t)(b0 + i + 0) * DIM + t];
      a1 += A[(size_t)(b0 + i + 1) * DIM + t];
      a2 += A[(size_t)(b0 + i + 2) * DIM + t];
      a3 += A[(size_t)(b0 + i + 3) * DIM + t];
    }
    for (; i < nmax; ++i) a0 += A[(size_t)(b0 + i) * DIM + t];
    atomicAdd(&sums[gfirst * DIM + t], (a0 + a1) + (a2 + a3));
  } else {
    float acc = 0.f;
    int cur = gfirst;
    for (int i = 0; i < nmax; i++) {
      int g = bb[i];
      if (g != cur) { atomicAdd(&sums[cur * DIM + t], acc); acc = 0.f; cur = g; }
      acc += A[(size_t)(b0 + i) * DIM + t];
    }
    atomicAdd(&sums[cur * DIM + t], acc);
  }
}

__global__ void k_cnts(const int* __restrict__ batch, float* __restrict__ cnts) {
  int g = threadIdx.x;  // 128
  int lo = 0, hi = NN;
  while (lo < hi) { int mid = (lo + hi) >> 1; if (batch[mid] < g) lo = mid + 1; else hi = mid; }
  int a = lo;
  lo = 0; hi = NN;
  while (lo < hi) { int mid = (lo + hi) >> 1; if (batch[mid] < g + 1) lo = mid + 1; else hi = mid; }
  cnts[g] = (float)(lo - a);
}

// ---------------- Head ----------------
__global__ void k_head(const float* __restrict__ sums, const float* __restrict__ cnts,
                       const float* __restrict__ W1, const float* __restrict__ b1,
                       const float* __restrict__ W2, const float* __restrict__ b2,
                       float* __restrict__ out) {
  int g = blockIdx.x, t = threadIdx.x;  // 64
  __shared__ float p[128];
  float ic = 1.f / fmaxf(cnts[g], 1.f);
  p[t] = sums[g * DIM + t] * ic;
  p[t + 64] = sums[g * DIM + 64 + t] * ic;
  __syncthreads();
  float z = b1[t];
  #pragma unroll 8
  for (int k = 0; k < 128; k++) z += p[k] * W1[k * FCD + t];
  z = fmaxf(z, 0.f);
  float sv = z * W2[t];
  #pragma unroll
  for (int o = 1; o < 64; o <<= 1) sv += __shfl_xor(sv, o);
  if (t == 0) out[g] = 1.f / (1.f + expf(-(sv + b2[0])));
}

extern "C" void kernel_launch(void* const* d_in, const int* in_sizes, int n_in,
                              void* d_out, int out_size, void* d_ws, size_t ws_size,
                              hipStream_t stream) {
  (void)in_sizes; (void)n_in; (void)out_size; (void)ws_size;
  const float* x     = (const float*)d_in[0];
  const int*   ei    = (const int*)d_in[1];
  const int*   batch = (const int*)d_in[2];
  const float* W_in  = (const float*)d_in[3];
  const float* b_in  = (const float*)d_in[4];
  const float* g_in  = (const float*)d_in[5];
  const float* be_in = (const float*)d_in[6];
  const float* W_mid = (const float*)d_in[7];
  const float* b_mid = (const float*)d_in[8];
  const float* g_mid = (const float*)d_in[9];
  const float* be_mid= (const float*)d_in[10];
  const float* W_out = (const float*)d_in[11];
  const float* b_out = (const float*)d_in[12];
  const float* g_out = (const float*)d_in[13];
  const float* be_out= (const float*)d_in[14];
  const float* W1    = (const float*)d_in[15];
  const float* b1    = (const float*)d_in[16];
  const float* W2    = (const float*)d_in[17];
  const float* b2    = (const float*)d_in[18];
  float* out = (float*)d_out;

  // workspace layout (~144 MB)
  char* p = (char*)d_ws;
  auto alloc = [&](size_t bytes) {
    char* r = p;
    p += (bytes + 255) & ~(size_t)255;
    return r;
  };
  float*  A      = (float*)alloc((size_t)NN * DIM * 4);   // node features (fp32, exact)
  half_t* Ah     = (half_t*)alloc((size_t)NN * DIM * 2);  // fp16 copy for next GEMM
  half_t* Xh     = (half_t*)alloc((size_t)NN * DIM * 2);  // input x (fp16)
  half_t* Bh     = (half_t*)alloc((size_t)NN * DIM * 2);  // scaled linear output (fp16)
  float*  dinv   = (float*)alloc((size_t)NN * 4);
  int*    rowptr = (int*)alloc((size_t)(NN + 1) * 4);
  int*    csrc   = (int*)alloc((size_t)NE * 4);
  int*    staged = (int*)alloc((size_t)NCH * ECH * 4);
  int*    offmat = (int*)alloc((size_t)NCH * (NBK + 1) * 4);
  int*    gtot   = (int*)alloc((size_t)(NBK + 1) * 4);
  int*    gbase  = (int*)alloc((size_t)(NBK + 1) * 4);
  float*  sums   = (float*)alloc((size_t)NGRAPH * DIM * 4);
  float*  cnts   = (float*)alloc((size_t)NGRAPH * 4);

  const int* rowp = ei;        // sources
  const int* colp = ei + NE;   // targets

  hipMemsetAsync(gtot, 0, (size_t)(NBK + 1) * 4, stream);
  hipMemsetAsync(sums, 0, (size_t)NGRAPH * DIM * 4, stream);

  k_bucketA<<<NCH, 256, 0, stream>>>(rowp, colp, staged, offmat, gtot);
  k_bsum<<<1, 256, 0, stream>>>(gtot, gbase, rowptr);
  k_csrB<<<NBK, 256, 0, stream>>>(staged, offmat, gbase, rowptr, dinv, csrc);
  k_cvt<<<(NN * DIM / 4 + 255) / 256, 256, 0, stream>>>(x, Xh);

  int gemm_grid = ((NN + 63) / 64) * 2;
  for (int l = 0; l < 8; l++) {
    const float *Wl, *bl, *gl, *bel;
    if (l == 0)      { Wl = W_in;  bl = b_in;  gl = g_in;  bel = be_in;  }
    else if (l == 7) { Wl = W_out; bl = b_out; gl = g_out; bel = be_out; }
    else             { Wl = W_mid; bl = b_mid; gl = g_mid; bel = be_mid; }
    const half_t* in = (l == 0) ? Xh : Ah;
    k_gemm<<<gemm_grid, 256, 0, stream>>>(in, Wl, dinv, Bh);
    int res = (l >= 2 && l <= 6 && (l % 2 == 0)) ? 1 : 0;
    k_agg<<<NN / 4, 256, 0, stream>>>((const half2_t*)Bh, A, (half2_t*)Ah,
                                      rowptr, csrc, dinv, bl, gl, bel, res);
  }

  k_pool<<<(NN + 63) / 64, 128, 0, stream>>>(A, batch, sums);
  k_cnts<<<1, 128, 0, stream>>>(batch, cnts);
  k_head<<<NGRAPH, 64, 0, stream>>>(sums, cnts, W1, b1, W2, b2, out);
}

// Round 10
// 949.655 us; speedup vs baseline: 1.6164x; 1.0426x over previous
//
#include <hip/hip_runtime.h>
#include <hip/hip_fp16.h>

#define NN 100000
#define NE 1600000
#define DIM 128
#define NGRAPH 128
#define FCD 64

#define NBK 391          // buckets of 256 target nodes: (NN+255)>>8
#define ECH 8192         // edges per pass-A chunk
#define NCH 196          // (NE + ECH - 1) / ECH
#define ECAP 8192        // pass-B per-bucket LDS capacity (avg ~4092, max ~4400)

typedef _Float16 half_t;
typedef _Float16 half2_t __attribute__((ext_vector_type(2)));
typedef _Float16 half4_t __attribute__((ext_vector_type(4)));

__device__ inline half2_t u2h(unsigned u) { union { unsigned u; half2_t h; } x; x.u = u; return x.h; }
__device__ inline unsigned h2u(half2_t h) { union { unsigned u; half2_t h; } x; x.h = h; return x.u; }

#if defined(__has_builtin)
#if __has_builtin(__builtin_amdgcn_fdot2)
#define HAS_FDOT2 1
#endif
#endif
#ifndef HAS_FDOT2
#define HAS_FDOT2 0
#endif

__device__ inline float dot2(half2_t a, half2_t b, float c) {
#if HAS_FDOT2
  return __builtin_amdgcn_fdot2(a, b, c, false);
#else
  return c + (float)a[0] * (float)b[0] + (float)a[1] * (float)b[1];
#endif
}

// ---------------- CSR build: two-level counting sort ----------------
__global__ __launch_bounds__(256) void k_bucketA(const int* __restrict__ row,
                                                 const int* __restrict__ col,
                                                 int* __restrict__ staged,
                                                 int* __restrict__ offmat,
                                                 int* __restrict__ gtot) {
  __shared__ int hist[NBK];
  __shared__ int sc[512];
  __shared__ int off[NBK + 1];
  __shared__ int fill[NBK];
  int b = blockIdx.x, t = threadIdx.x;
  int e0 = b * ECH;
  int n = NE - e0; if (n > ECH) n = ECH;
  for (int j = t; j < NBK; j += 256) { hist[j] = 0; fill[j] = 0; }
  __syncthreads();
  for (int i = t; i < n; i += 256) atomicAdd(&hist[col[e0 + i] >> 8], 1);
  __syncthreads();
  sc[t] = (t < NBK) ? hist[t] : 0;
  sc[t + 256] = (t + 256 < NBK) ? hist[t + 256] : 0;
  __syncthreads();
  #pragma unroll
  for (int o = 1; o < 512; o <<= 1) {
    int a0 = (t >= o) ? sc[t - o] : 0;
    int a1 = (t + 256 >= o) ? sc[t + 256 - o] : 0;
    __syncthreads();
    sc[t] += a0; sc[t + 256] += a1;
    __syncthreads();
  }
  if (t == 0) off[0] = 0;
  for (int j = t; j < NBK; j += 256) off[j + 1] = sc[j];
  for (int j = t; j < NBK; j += 256) if (hist[j]) atomicAdd(&gtot[j], hist[j]);
  __syncthreads();
  for (int j = t; j < NBK + 1; j += 256) offmat[b * (NBK + 1) + j] = off[j];
  for (int i = t; i < n; i += 256) {
    int c = col[e0 + i], r = row[e0 + i];
    int bkt = c >> 8;
    int pos = off[bkt] + atomicAdd(&fill[bkt], 1);
    staged[e0 + pos] = (r << 8) | (c & 255);
  }
}

__global__ void k_bsum(const int* __restrict__ gtot, int* __restrict__ gbase,
                       int* __restrict__ rowptr) {
  __shared__ int sc[512];
  int t = threadIdx.x;  // 256
  sc[t] = (t < NBK) ? gtot[t] : 0;
  sc[t + 256] = (t + 256 < NBK) ? gtot[t + 256] : 0;
  __syncthreads();
  #pragma unroll
  for (int o = 1; o < 512; o <<= 1) {
    int a0 = (t >= o) ? sc[t - o] : 0;
    int a1 = (t + 256 >= o) ? sc[t + 256 - o] : 0;
    __syncthreads();
    sc[t] += a0; sc[t + 256] += a1;
    __syncthreads();
  }
  if (t == 0) { gbase[0] = 0; rowptr[NN] = NE; }
  for (int j = t; j < NBK; j += 256) gbase[j + 1] = sc[j];
}

__global__ __launch_bounds__(256) void k_csrB(const int* __restrict__ staged,
                                              const int* __restrict__ offmat,
                                              const int* __restrict__ gbase,
                                              int* __restrict__ rowptr,
                                              float* __restrict__ dinv,
                                              int* __restrict__ csrc) {
  __shared__ int pay[ECAP];
  __shared__ int csn[256];
  __shared__ int nhist[256];
  __shared__ int nscan[256];
  __shared__ int nb[256];
  __shared__ int nfill[256];
  int bkt = blockIdx.x, t = threadIdx.x;
  int gb = gbase[bkt];
  int off = 0, cnt = 0;
  if (t < NCH) {
    int base = t * (NBK + 1) + bkt;
    off = offmat[base];
    cnt = offmat[base + 1] - off;
  }
  csn[t] = cnt;
  __syncthreads();
  #pragma unroll
  for (int o = 1; o < 256; o <<= 1) {
    int a = (t >= o) ? csn[t - o] : 0;
    __syncthreads();
    csn[t] += a;
    __syncthreads();
  }
  int lb = csn[t] - cnt;
  int total = csn[255];
  if (t < NCH) {
    const int* src = staged + t * ECH + off;
    for (int i = 0; i < cnt; i++) pay[lb + i] = src[i];
  }
  nhist[t] = 0; nfill[t] = 0;
  __syncthreads();
  for (int i = t; i < total; i += 256) atomicAdd(&nhist[pay[i] & 255], 1);
  __syncthreads();
  nscan[t] = nhist[t];
  __syncthreads();
  #pragma unroll
  for (int o = 1; o < 256; o <<= 1) {
    int a = (t >= o) ? nscan[t - o] : 0;
    __syncthreads();
    nscan[t] += a;
    __syncthreads();
  }
  nb[t] = nscan[t] - nhist[t];
  int v = bkt * 256 + t;
  if (v < NN) {
    rowptr[v] = gb + nb[t];
    dinv[v] = rsqrtf((float)(nhist[t] + 1));   // +1 self loop
  }
  __syncthreads();
  for (int i = t; i < total; i += 256) {
    int p = pay[i];
    int cl = p & 255;
    int pos = nb[cl] + atomicAdd(&nfill[cl], 1);
    csrc[gb + pos] = p >> 8;
  }
}

// ---------------- x fp32 -> fp16 (layer-0 input only) ----------------
__global__ void k_cvt(const float* __restrict__ x, half_t* __restrict__ Xh) {
  int i = blockIdx.x * 256 + threadIdx.x;
  if ((size_t)i * 4 < (size_t)NN * DIM) {
    float4 v = *(const float4*)&x[(size_t)i * 4];
    half4_t h; h[0] = (half_t)v.x; h[1] = (half_t)v.y; h[2] = (half_t)v.z; h[3] = (half_t)v.w;
    *(half4_t*)&Xh[(size_t)i * 4] = h;
  }
}

// ---------------- GEMM: O[n][j] = dinv[n] * sum_k X[n][k] * W[k][j], fp16 in/out --
__global__ __launch_bounds__(256) void k_gemm(const half_t* __restrict__ X,
                                              const float* __restrict__ W,
                                              const float* __restrict__ dinv,
                                              half_t* __restrict__ O) {
  __shared__ unsigned Xs[32 * 68];  // [k-pair][row] half2-as-uint, stride 68
  __shared__ unsigned Ws[32 * 68];  // [k-pair][col] half2 (W[k][j], W[k+1][j])
  int bid = blockIdx.x;
  int n0 = (bid >> 1) * 64;
  int jb = (bid & 1) * 64;
  int t = threadIdx.x;
  int tx = t & 15, ty = t >> 4;
  float acc[4][4] = {};
  for (int kb = 0; kb < 128; kb += 64) {
    __syncthreads();
    #pragma unroll
    for (int i = 0; i < 2; i++) {
      int e = t + i * 256;             // 0..511
      int row = e >> 3;                // node row 0..63
      int seg = e & 7;                 // 8 segments x 8 halfs = full 64-half chunk
      int n = n0 + row;
      uint4 v = make_uint4(0, 0, 0, 0);
      if (n < NN) v = *(const uint4*)&X[(size_t)n * DIM + kb + seg * 8];
      int kp0 = seg * 4;               // k-pair 0..28
      Xs[(kp0 + 0) * 68 + row] = v.x;
      Xs[(kp0 + 1) * 68 + row] = v.y;
      Xs[(kp0 + 2) * 68 + row] = v.z;
      Xs[(kp0 + 3) * 68 + row] = v.w;
    }
    #pragma unroll
    for (int i = 0; i < 2; i++) {
      int e = t + i * 256;      // 0..511
      int kp = e >> 4;          // 0..31
      int jq = (e & 15) * 4;
      float4 a = *(const float4*)&W[(size_t)(kb + 2 * kp) * DIM + jb + jq];
      float4 b = *(const float4*)&W[(size_t)(kb + 2 * kp + 1) * DIM + jb + jq];
      half2_t p0; p0[0] = (half_t)a.x; p0[1] = (half_t)b.x;
      half2_t p1; p1[0] = (half_t)a.y; p1[1] = (half_t)b.y;
      half2_t p2; p2[0] = (half_t)a.z; p2[1] = (half_t)b.z;
      half2_t p3; p3[0] = (half_t)a.w; p3[1] = (half_t)b.w;
      *(uint4*)&Ws[kp * 68 + jq] = make_uint4(h2u(p0), h2u(p1), h2u(p2), h2u(p3));
    }
    __syncthreads();
    #pragma unroll 8
    for (int kp = 0; kp < 32; kp++) {
      uint4 au = *(const uint4*)&Xs[kp * 68 + ty * 4];
      uint4 bu = *(const uint4*)&Ws[kp * 68 + tx * 4];
      half2_t a0 = u2h(au.x), a1 = u2h(au.y), a2 = u2h(au.z), a3 = u2h(au.w);
      half2_t b0 = u2h(bu.x), b1 = u2h(bu.y), b2 = u2h(bu.z), b3 = u2h(bu.w);
      acc[0][0] = dot2(a0, b0, acc[0][0]); acc[0][1] = dot2(a0, b1, acc[0][1]);
      acc[0][2] = dot2(a0, b2, acc[0][2]); acc[0][3] = dot2(a0, b3, acc[0][3]);
      acc[1][0] = dot2(a1, b0, acc[1][0]); acc[1][1] = dot2(a1, b1, acc[1][1]);
      acc[1][2] = dot2(a1, b2, acc[1][2]); acc[1][3] = dot2(a1, b3, acc[1][3]);
      acc[2][0] = dot2(a2, b0, acc[2][0]); acc[2][1] = dot2(a2, b1, acc[2][1]);
      acc[2][2] = dot2(a2, b2, acc[2][2]); acc[2][3] = dot2(a2, b3, acc[2][3]);
      acc[3][0] = dot2(a3, b0, acc[3][0]); acc[3][1] = dot2(a3, b1, acc[3][1]);
      acc[3][2] = dot2(a3, b2, acc[3][2]); acc[3][3] = dot2(a3, b3, acc[3][3]);
    }
  }
  #pragma unroll
  for (int r = 0; r < 4; r++) {
    int n = n0 + ty * 4 + r;
    if (n < NN) {
      float dv = dinv[n];
      half4_t h;
      h[0] = (half_t)(acc[r][0] * dv);
      h[1] = (half_t)(acc[r][1] * dv);
      h[2] = (half_t)(acc[r][2] * dv);
      h[3] = (half_t)(acc[r][3] * dv);
      *(half4_t*)&O[(size_t)n * DIM + jb + tx * 4] = h;
    }
  }
}

// ---------------- Aggregation + bias + LayerNorm + ReLU + residual ----------------
// one wave per node; lane = 16-lane group g (edge phase 0..3) x feature octet fl.
// One dwordx4 load serves 4 edges. Node state Ah is fp16 (sole copy).
__global__ __launch_bounds__(256) void k_agg(const half2_t* __restrict__ Hh,
                      half2_t* __restrict__ Ah,
                      const int* __restrict__ rowptr, const int* __restrict__ csrc,
                      const float* __restrict__ dinv,
                      const float* __restrict__ bias, const float* __restrict__ gamma,
                      const float* __restrict__ beta, int res) {
  int tid = threadIdx.x;
  int lane = tid & 63;
  int v = blockIdx.x * 4 + (tid >> 6);   // one node per wave; NN % 4 == 0
  int g = lane >> 4;                     // edge phase 0..3
  int fl = lane & 15;                    // feature octet 0..15 (8 halfs)
  int s0 = rowptr[v];
  int cnt = rowptr[v + 1] - s0;
  const uint4* Hq = (const uint4*)Hh;    // 16 uint4 per 128-half row
  half2_t a0 = u2h(0u), a1 = u2h(0u), a2 = u2h(0u), a3 = u2h(0u);
  for (int i = g; i < cnt; i += 8) {     // phases g, g+4 per iter; union covers all
    int j = i + 4;
    int jc = (j < cnt) ? j : (cnt - 1);
    int e0 = csrc[s0 + i];
    int e1 = csrc[s0 + jc];
    uint4 q0 = Hq[(size_t)e0 * 16 + fl];
    uint4 q1 = Hq[(size_t)e1 * 16 + fl];
    a0 += u2h(q0.x); a1 += u2h(q0.y); a2 += u2h(q0.z); a3 += u2h(q0.w);
    if (j < cnt) { a0 += u2h(q1.x); a1 += u2h(q1.y); a2 += u2h(q1.z); a3 += u2h(q1.w); }
  }
  // to fp32, reduce the 4 edge phases (lanes l, l^16, l^32 hold same features)
  float f0 = (float)a0[0], f1 = (float)a0[1], f2 = (float)a1[0], f3 = (float)a1[1];
  float f4 = (float)a2[0], f5 = (float)a2[1], f6 = (float)a3[0], f7 = (float)a3[1];
  f0 += __shfl_xor(f0, 16); f0 += __shfl_xor(f0, 32);
  f1 += __shfl_xor(f1, 16); f1 += __shfl_xor(f1, 32);
  f2 += __shfl_xor(f2, 16); f2 += __shfl_xor(f2, 32);
  f3 += __shfl_xor(f3, 16); f3 += __shfl_xor(f3, 32);
  f4 += __shfl_xor(f4, 16); f4 += __shfl_xor(f4, 32);
  f5 += __shfl_xor(f5, 16); f5 += __shfl_xor(f5, 32);
  f6 += __shfl_xor(f6, 16); f6 += __shfl_xor(f6, 32);
  f7 += __shfl_xor(f7, 16); f7 += __shfl_xor(f7, 32);
  // self-loop in fp32
  uint4 qs = Hq[(size_t)v * 16 + fl];
  half2_t s0h = u2h(qs.x), s1h = u2h(qs.y), s2h = u2h(qs.z), s3h = u2h(qs.w);
  f0 += (float)s0h[0]; f1 += (float)s0h[1]; f2 += (float)s1h[0]; f3 += (float)s1h[1];
  f4 += (float)s2h[0]; f5 += (float)s2h[1]; f6 += (float)s3h[0]; f7 += (float)s3h[1];
  float dv = dinv[v];
  float4 ba = *(const float4*)&bias[fl * 8];
  float4 bb = *(const float4*)&bias[fl * 8 + 4];
  f0 = f0 * dv + ba.x; f1 = f1 * dv + ba.y; f2 = f2 * dv + ba.z; f3 = f3 * dv + ba.w;
  f4 = f4 * dv + bb.x; f5 = f5 * dv + bb.y; f6 = f6 * dv + bb.z; f7 = f7 * dv + bb.w;
  // LayerNorm stats over 16 octets (values replicated across phases)
  float s  = ((f0 + f1) + (f2 + f3)) + ((f4 + f5) + (f6 + f7));
  float ss = ((f0 * f0 + f1 * f1) + (f2 * f2 + f3 * f3))
           + ((f4 * f4 + f5 * f5) + (f6 * f6 + f7 * f7));
  #pragma unroll
  for (int o = 1; o < 16; o <<= 1) { s += __shfl_xor(s, o); ss += __shfl_xor(ss, o); }
  float mu = s * (1.f / 128.f);
  float var = ss * (1.f / 128.f) - mu * mu;
  float rs = rsqrtf(var + 1e-5f);
  // phase g writes features fl*8 + 2g, 2g+1
  float pa = (g == 0) ? f0 : (g == 1) ? f2 : (g == 2) ? f4 : f6;
  float pb = (g == 0) ? f1 : (g == 1) ? f3 : (g == 2) ? f5 : f7;
  int fi = fl * 8 + g * 2;
  float2 g2 = *(const float2*)&gamma[fi];
  float2 e2 = *(const float2*)&beta[fi];
  float y0 = fmaxf((pa - mu) * rs * g2.x + e2.x, 0.f);
  float y1 = fmaxf((pb - mu) * rs * g2.y + e2.y, 0.f);
  half2_t* Ap = &Ah[(size_t)v * 64 + (fi >> 1)];
  if (res) { half2_t o2 = *Ap; y0 += (float)o2[0]; y1 += (float)o2[1]; }
  half2_t w; w[0] = (half_t)y0; w[1] = (half_t)y1;
  *Ap = w;
}

// ---------------- Global mean pool (batch is sorted, Ah fp16) ----------------
// 64 threads/block = 1 wave; lane t owns feature pair (2t, 2t+1); CH=64 rows.
__global__ __launch_bounds__(64) void k_pool(const half2_t* __restrict__ Ah,
                                             const int* __restrict__ batch,
                                             float* __restrict__ sums) {
  const int CH = 64;
  int b0 = blockIdx.x * CH;
  int t = threadIdx.x;  // 64
  int nmax = NN - b0; if (nmax > CH) nmax = CH;
  __shared__ int bb[CH];
  bb[t] = (b0 + t < NN) ? batch[b0 + t] : -1;
  __syncthreads();
  int gfirst = bb[0], glast = bb[nmax - 1];
  if (gfirst == glast) {
    float p0 = 0.f, p1 = 0.f, q0 = 0.f, q1 = 0.f, r0 = 0.f, r1 = 0.f, u0 = 0.f, u1 = 0.f;
    int i = 0;
    for (; i + 4 <= nmax; i += 4) {
      half2_t h0 = Ah[(size_t)(b0 + i + 0) * 64 + t];
      half2_t h1 = Ah[(size_t)(b0 + i + 1) * 64 + t];
      half2_t h2 = Ah[(size_t)(b0 + i + 2) * 64 + t];
      half2_t h3 = Ah[(size_t)(b0 + i + 3) * 64 + t];
      p0 += (float)h0[0]; p1 += (float)h0[1];
      q0 += (float)h1[0]; q1 += (float)h1[1];
      r0 += (float)h2[0]; r1 += (float)h2[1];
      u0 += (float)h3[0]; u1 += (float)h3[1];
    }
    for (; i < nmax; ++i) {
      half2_t h = Ah[(size_t)(b0 + i) * 64 + t];
      p0 += (float)h[0]; p1 += (float)h[1];
    }
    atomicAdd(&sums[gfirst * DIM + 2 * t], (p0 + q0) + (r0 + u0));
    atomicAdd(&sums[gfirst * DIM + 2 * t + 1], (p1 + q1) + (r1 + u1));
  } else {
    float s0 = 0.f, s1 = 0.f;
    int cur = gfirst;
    for (int i = 0; i < nmax; i++) {
      int g = bb[i];
      if (g != cur) {
        atomicAdd(&sums[cur * DIM + 2 * t], s0);
        atomicAdd(&sums[cur * DIM + 2 * t + 1], s1);
        s0 = s1 = 0.f; cur = g;
      }
      half2_t h = Ah[(size_t)(b0 + i) * 64 + t];
      s0 += (float)h[0]; s1 += (float)h[1];
    }
    atomicAdd(&sums[cur * DIM + 2 * t], s0);
    atomicAdd(&sums[cur * DIM + 2 * t + 1], s1);
  }
}

__global__ void k_cnts(const int* __restrict__ batch, float* __restrict__ cnts) {
  int g = threadIdx.x;  // 128
  int lo = 0, hi = NN;
  while (lo < hi) { int mid = (lo + hi) >> 1; if (batch[mid] < g) lo = mid + 1; else hi = mid; }
  int a = lo;
  lo = 0; hi = NN;
  while (lo < hi) { int mid = (lo + hi) >> 1; if (batch[mid] < g + 1) lo = mid + 1; else hi = mid; }
  cnts[g] = (float)(lo - a);
}

// ---------------- Head ----------------
__global__ void k_head(const float* __restrict__ sums, const float* __restrict__ cnts,
                       const float* __restrict__ W1, const float* __restrict__ b1,
                       const float* __restrict__ W2, const float* __restrict__ b2,
                       float* __restrict__ out) {
  int g = blockIdx.x, t = threadIdx.x;  // 64
  __shared__ float p[128];
  float ic = 1.f / fmaxf(cnts[g], 1.f);
  p[t] = sums[g * DIM + t] * ic;
  p[t + 64] = sums[g * DIM + 64 + t] * ic;
  __syncthreads();
  float z = b1[t];
  #pragma unroll 8
  for (int k = 0; k < 128; k++) z += p[k] * W1[k * FCD + t];
  z = fmaxf(z, 0.f);
  float sv = z * W2[t];
  #pragma unroll
  for (int o = 1; o < 64; o <<= 1) sv += __shfl_xor(sv, o);
  if (t == 0) out[g] = 1.f / (1.f + expf(-(sv + b2[0])));
}

extern "C" void kernel_launch(void* const* d_in, const int* in_sizes, int n_in,
                              void* d_out, int out_size, void* d_ws, size_t ws_size,
                              hipStream_t stream) {
  (void)in_sizes; (void)n_in; (void)out_size; (void)ws_size;
  const float* x     = (const float*)d_in[0];
  const int*   ei    = (const int*)d_in[1];
  const int*   batch = (const int*)d_in[2];
  const float* W_in  = (const float*)d_in[3];
  const float* b_in  = (const float*)d_in[4];
  const float* g_in  = (const float*)d_in[5];
  const float* be_in = (const float*)d_in[6];
  const float* W_mid = (const float*)d_in[7];
  const float* b_mid = (const float*)d_in[8];
  const float* g_mid = (const float*)d_in[9];
  const float* be_mid= (const float*)d_in[10];
  const float* W_out = (const float*)d_in[11];
  const float* b_out = (const float*)d_in[12];
  const float* g_out = (const float*)d_in[13];
  const float* be_out= (const float*)d_in[14];
  const float* W1    = (const float*)d_in[15];
  const float* b1    = (const float*)d_in[16];
  const float* W2    = (const float*)d_in[17];
  const float* b2    = (const float*)d_in[18];
  float* out = (float*)d_out;

  // workspace layout (~95 MB)
  char* p = (char*)d_ws;
  auto alloc = [&](size_t bytes) {
    char* r = p;
    p += (bytes + 255) & ~(size_t)255;
    return r;
  };
  half_t* Ah     = (half_t*)alloc((size_t)NN * DIM * 2);  // node features (fp16, sole copy)
  half_t* Xh     = (half_t*)alloc((size_t)NN * DIM * 2);  // input x (fp16)
  half_t* Bh     = (half_t*)alloc((size_t)NN * DIM * 2);  // scaled linear output (fp16)
  float*  dinv   = (float*)alloc((size_t)NN * 4);
  int*    rowptr = (int*)alloc((size_t)(NN + 1) * 4);
  int*    csrc   = (int*)alloc((size_t)NE * 4);
  int*    staged = (int*)alloc((size_t)NCH * ECH * 4);
  int*    offmat = (int*)alloc((size_t)NCH * (NBK + 1) * 4);
  int*    gtot   = (int*)alloc((size_t)(NBK + 1) * 4);
  int*    gbase  = (int*)alloc((size_t)(NBK + 1) * 4);
  float*  sums   = (float*)alloc((size_t)NGRAPH * DIM * 4);
  float*  cnts   = (float*)alloc((size_t)NGRAPH * 4);

  const int* rowp = ei;        // sources
  const int* colp = ei + NE;   // targets

  hipMemsetAsync(gtot, 0, (size_t)(NBK + 1) * 4, stream);
  hipMemsetAsync(sums, 0, (size_t)NGRAPH * DIM * 4, stream);

  k_bucketA<<<NCH, 256, 0, stream>>>(rowp, colp, staged, offmat, gtot);
  k_bsum<<<1, 256, 0, stream>>>(gtot, gbase, rowptr);
  k_csrB<<<NBK, 256, 0, stream>>>(staged, offmat, gbase, rowptr, dinv, csrc);
  k_cvt<<<(NN * DIM / 4 + 255) / 256, 256, 0, stream>>>(x, Xh);

  int gemm_grid = ((NN + 63) / 64) * 2;
  for (int l = 0; l < 8; l++) {
    const float *Wl, *bl, *gl, *bel;
    if (l == 0)      { Wl = W_in;  bl = b_in;  gl = g_in;  bel = be_in;  }
    else if (l == 7) { Wl = W_out; bl = b_out; gl = g_out; bel = be_out; }
    else             { Wl = W_mid; bl = b_mid; gl = g_mid; bel = be_mid; }
    const half_t* in = (l == 0) ? Xh : Ah;
    k_gemm<<<gemm_grid, 256, 0, stream>>>(in, Wl, dinv, Bh);
    int res = (l >= 2 && l <= 6 && (l % 2 == 0)) ? 1 : 0;
    k_agg<<<NN / 4, 256, 0, stream>>>((const half2_t*)Bh, (half2_t*)Ah,
                                      rowptr, csrc, dinv, bl, gl, bel, res);
  }

  k_pool<<<(NN + 63) / 64, 64, 0, stream>>>((const half2_t*)Ah, batch, sums);
  k_cnts<<<1, 128, 0, stream>>>(batch, cnts);
  k_head<<<NGRAPH, 64, 0, stream>>>(sums, cnts, W1, b1, W2, b2, out);
}

// Round 11
// 930.913 us; speedup vs baseline: 1.6489x; 1.0201x over previous
//
#include <hip/hip_runtime.h>
#include <hip/hip_fp16.h>

#define NN 100000
#define NE 1600000
#define DIM 128
#define NGRAPH 128
#define FCD 64

#define NBK 391          // buckets of 256 target nodes: (NN+255)>>8
#define ECH 8192         // edges per pass-A chunk
#define NCH 196          // (NE + ECH - 1) / ECH
#define ECAP 8192        // pass-B per-bucket LDS capacity (avg ~4092, max ~4400)

typedef _Float16 half_t;
typedef _Float16 half2_t __attribute__((ext_vector_type(2)));
typedef _Float16 half4_t __attribute__((ext_vector_type(4)));

__device__ inline half2_t u2h(unsigned u) { union { unsigned u; half2_t h; } x; x.u = u; return x.h; }
__device__ inline unsigned h2u(half2_t h) { union { unsigned u; half2_t h; } x; x.h = h; return x.u; }

#if defined(__has_builtin)
#if __has_builtin(__builtin_amdgcn_fdot2)
#define HAS_FDOT2 1
#endif
#endif
#ifndef HAS_FDOT2
#define HAS_FDOT2 0
#endif

__device__ inline float dot2(half2_t a, half2_t b, float c) {
#if HAS_FDOT2
  return __builtin_amdgcn_fdot2(a, b, c, false);
#else
  return c + (float)a[0] * (float)b[0] + (float)a[1] * (float)b[1];
#endif
}

// ---------------- CSR build: two-level counting sort ----------------
__global__ __launch_bounds__(256) void k_bucketA(const int* __restrict__ row,
                                                 const int* __restrict__ col,
                                                 int* __restrict__ staged,
                                                 int* __restrict__ offmat,
                                                 int* __restrict__ gtot) {
  __shared__ int hist[NBK];
  __shared__ int sc[512];
  __shared__ int off[NBK + 1];
  __shared__ int fill[NBK];
  int b = blockIdx.x, t = threadIdx.x;
  int e0 = b * ECH;
  int n = NE - e0; if (n > ECH) n = ECH;
  for (int j = t; j < NBK; j += 256) { hist[j] = 0; fill[j] = 0; }
  __syncthreads();
  for (int i = t; i < n; i += 256) atomicAdd(&hist[col[e0 + i] >> 8], 1);
  __syncthreads();
  sc[t] = (t < NBK) ? hist[t] : 0;
  sc[t + 256] = (t + 256 < NBK) ? hist[t + 256] : 0;
  __syncthreads();
  #pragma unroll
  for (int o = 1; o < 512; o <<= 1) {
    int a0 = (t >= o) ? sc[t - o] : 0;
    int a1 = (t + 256 >= o) ? sc[t + 256 - o] : 0;
    __syncthreads();
    sc[t] += a0; sc[t + 256] += a1;
    __syncthreads();
  }
  if (t == 0) off[0] = 0;
  for (int j = t; j < NBK; j += 256) off[j + 1] = sc[j];
  for (int j = t; j < NBK; j += 256) if (hist[j]) atomicAdd(&gtot[j], hist[j]);
  __syncthreads();
  for (int j = t; j < NBK + 1; j += 256) offmat[b * (NBK + 1) + j] = off[j];
  for (int i = t; i < n; i += 256) {
    int c = col[e0 + i], r = row[e0 + i];
    int bkt = c >> 8;
    int pos = off[bkt] + atomicAdd(&fill[bkt], 1);
    staged[e0 + pos] = (r << 8) | (c & 255);
  }
}

__global__ void k_bsum(const int* __restrict__ gtot, int* __restrict__ gbase,
                       int* __restrict__ rowptr) {
  __shared__ int sc[512];
  int t = threadIdx.x;  // 256
  sc[t] = (t < NBK) ? gtot[t] : 0;
  sc[t + 256] = (t + 256 < NBK) ? gtot[t + 256] : 0;
  __syncthreads();
  #pragma unroll
  for (int o = 1; o < 512; o <<= 1) {
    int a0 = (t >= o) ? sc[t - o] : 0;
    int a1 = (t + 256 >= o) ? sc[t + 256 - o] : 0;
    __syncthreads();
    sc[t] += a0; sc[t + 256] += a1;
    __syncthreads();
  }
  if (t == 0) { gbase[0] = 0; rowptr[NN] = NE; }
  for (int j = t; j < NBK; j += 256) gbase[j + 1] = sc[j];
}

__global__ __launch_bounds__(256) void k_csrB(const int* __restrict__ staged,
                                              const int* __restrict__ offmat,
                                              const int* __restrict__ gbase,
                                              int* __restrict__ rowptr,
                                              float* __restrict__ dinv,
                                              int* __restrict__ csrc) {
  __shared__ int pay[ECAP];
  __shared__ int csn[256];
  __shared__ int nhist[256];
  __shared__ int nscan[256];
  __shared__ int nb[256];
  __shared__ int nfill[256];
  int bkt = blockIdx.x, t = threadIdx.x;
  int gb = gbase[bkt];
  int off = 0, cnt = 0;
  if (t < NCH) {
    int base = t * (NBK + 1) + bkt;
    off = offmat[base];
    cnt = offmat[base + 1] - off;
  }
  csn[t] = cnt;
  __syncthreads();
  #pragma unroll
  for (int o = 1; o < 256; o <<= 1) {
    int a = (t >= o) ? csn[t - o] : 0;
    __syncthreads();
    csn[t] += a;
    __syncthreads();
  }
  int lb = csn[t] - cnt;
  int total = csn[255];
  if (t < NCH) {
    const int* src = staged + t * ECH + off;
    for (int i = 0; i < cnt; i++) pay[lb + i] = src[i];
  }
  nhist[t] = 0; nfill[t] = 0;
  __syncthreads();
  for (int i = t; i < total; i += 256) atomicAdd(&nhist[pay[i] & 255], 1);
  __syncthreads();
  nscan[t] = nhist[t];
  __syncthreads();
  #pragma unroll
  for (int o = 1; o < 256; o <<= 1) {
    int a = (t >= o) ? nscan[t - o] : 0;
    __syncthreads();
    nscan[t] += a;
    __syncthreads();
  }
  nb[t] = nscan[t] - nhist[t];
  int v = bkt * 256 + t;
  if (v < NN) {
    rowptr[v] = gb + nb[t];
    dinv[v] = rsqrtf((float)(nhist[t] + 1));   // +1 self loop
  }
  __syncthreads();
  for (int i = t; i < total; i += 256) {
    int p = pay[i];
    int cl = p & 255;
    int pos = nb[cl] + atomicAdd(&nfill[cl], 1);
    csrc[gb + pos] = p >> 8;
  }
}

// ---------------- x fp32 -> fp16 (layer-0 input only) ----------------
__global__ void k_cvt(const float* __restrict__ x, half_t* __restrict__ Xh) {
  int i = blockIdx.x * 256 + threadIdx.x;
  if ((size_t)i * 4 < (size_t)NN * DIM) {
    float4 v = *(const float4*)&x[(size_t)i * 4];
    half4_t h; h[0] = (half_t)v.x; h[1] = (half_t)v.y; h[2] = (half_t)v.z; h[3] = (half_t)v.w;
    *(half4_t*)&Xh[(size_t)i * 4] = h;
  }
}

// ---------------- GEMM: O[n][j] = dinv[n] * sum_k X[n][k] * W[k][j], fp16 in/out --
// One block = 64 rows x 128 cols (full width): X rows fetched ONCE per layer.
// dot2 fp16 compute, fp32 accumulate. Micro-tile 4x8 per thread.
// Ws padded stride-9-per-8 uints -> conflict-free b128 reads.
__global__ __launch_bounds__(256) void k_gemm(const half_t* __restrict__ X,
                                              const float* __restrict__ W,
                                              const float* __restrict__ dinv,
                                              half_t* __restrict__ O) {
  __shared__ unsigned Xs[32 * 68];   // [k-pair][row] half2-as-uint
  __shared__ unsigned Ws[32 * 144];  // [k-pair][col(+pad)] half2 (W[2kp][j],W[2kp+1][j])
  int n0 = blockIdx.x * 64;
  int t = threadIdx.x;
  int tx = t & 15, ty = t >> 4;      // cols tx*8..+7, rows ty*4..+3
  float acc[4][8] = {};
  for (int kb = 0; kb < 128; kb += 64) {
    __syncthreads();
    #pragma unroll
    for (int i = 0; i < 2; i++) {
      int e = t + i * 256;             // 0..511
      int row = e >> 3;                // node row 0..63
      int seg = e & 7;                 // 8 segments x 8 halfs = full 64-half chunk
      int n = n0 + row;
      uint4 v = make_uint4(0, 0, 0, 0);
      if (n < NN) v = *(const uint4*)&X[(size_t)n * DIM + kb + seg * 8];
      int kp0 = seg * 4;
      Xs[(kp0 + 0) * 68 + row] = v.x;
      Xs[(kp0 + 1) * 68 + row] = v.y;
      Xs[(kp0 + 2) * 68 + row] = v.z;
      Xs[(kp0 + 3) * 68 + row] = v.w;
    }
    #pragma unroll
    for (int i = 0; i < 4; i++) {
      int e = t + i * 256;      // 0..1023
      int kp = e >> 5;          // 0..31
      int j0 = (e & 31) * 4;    // 0..124
      float4 a = *(const float4*)&W[(size_t)(kb + 2 * kp) * DIM + j0];
      float4 b = *(const float4*)&W[(size_t)(kb + 2 * kp + 1) * DIM + j0];
      half2_t p0; p0[0] = (half_t)a.x; p0[1] = (half_t)b.x;
      half2_t p1; p1[0] = (half_t)a.y; p1[1] = (half_t)b.y;
      half2_t p2; p2[0] = (half_t)a.z; p2[1] = (half_t)b.z;
      half2_t p3; p3[0] = (half_t)a.w; p3[1] = (half_t)b.w;
      int off = j0 + (j0 >> 3);   // +1 pad per 8 uints
      *(uint4*)&Ws[kp * 144 + off] = make_uint4(h2u(p0), h2u(p1), h2u(p2), h2u(p3));
    }
    __syncthreads();
    #pragma unroll 4
    for (int kp = 0; kp < 32; kp++) {
      uint4 au = *(const uint4*)&Xs[kp * 68 + ty * 4];
      uint4 b0 = *(const uint4*)&Ws[kp * 144 + tx * 9];
      uint4 b1 = *(const uint4*)&Ws[kp * 144 + tx * 9 + 4];
      half2_t a[4] = { u2h(au.x), u2h(au.y), u2h(au.z), u2h(au.w) };
      half2_t b[8] = { u2h(b0.x), u2h(b0.y), u2h(b0.z), u2h(b0.w),
                       u2h(b1.x), u2h(b1.y), u2h(b1.z), u2h(b1.w) };
      #pragma unroll
      for (int r = 0; r < 4; r++)
        #pragma unroll
        for (int c = 0; c < 8; c++)
          acc[r][c] = dot2(a[r], b[c], acc[r][c]);
    }
  }
  #pragma unroll
  for (int r = 0; r < 4; r++) {
    int n = n0 + ty * 4 + r;
    if (n < NN) {
      float dv = dinv[n];
      half2_t h[4];
      #pragma unroll
      for (int c = 0; c < 4; c++) {
        half2_t p; p[0] = (half_t)(acc[r][2 * c] * dv); p[1] = (half_t)(acc[r][2 * c + 1] * dv);
        h[c] = p;
      }
      uint4 o4 = make_uint4(h2u(h[0]), h2u(h[1]), h2u(h[2]), h2u(h[3]));
      *(uint4*)&O[(size_t)n * DIM + tx * 8] = o4;
    }
  }
}

// ---------------- Aggregation + bias + LayerNorm + ReLU + residual ----------------
// one wave per node; lane = 16-lane group g (edge phase 0..3) x feature octet fl.
// 16 edges in flight per iteration (4 index loads + 4 dwordx4 gathers).
__global__ __launch_bounds__(256) void k_agg(const half2_t* __restrict__ Hh,
                      half2_t* __restrict__ Ah,
                      const int* __restrict__ rowptr, const int* __restrict__ csrc,
                      const float* __restrict__ dinv,
                      const float* __restrict__ bias, const float* __restrict__ gamma,
                      const float* __restrict__ beta, int res) {
  int tid = threadIdx.x;
  int lane = tid & 63;
  int v = blockIdx.x * 4 + (tid >> 6);   // one node per wave; NN % 4 == 0
  int g = lane >> 4;                     // edge phase 0..3
  int fl = lane & 15;                    // feature octet 0..15 (8 halfs)
  int s0 = rowptr[v];
  int cnt = rowptr[v + 1] - s0;
  const uint4* Hq = (const uint4*)Hh;    // 16 uint4 per 128-half row
  half2_t a0 = u2h(0u), a1 = u2h(0u), a2 = u2h(0u), a3 = u2h(0u);
  for (int i = g; i < cnt; i += 16) {    // phases i, i+4, i+8, i+12
    int j1 = i + 4, j2 = i + 8, j3 = i + 12;
    int c1 = min(j1, cnt - 1);
    int c2 = min(j2, cnt - 1);
    int c3 = min(j3, cnt - 1);
    int e0 = csrc[s0 + i];
    int e1 = csrc[s0 + c1];
    int e2 = csrc[s0 + c2];
    int e3 = csrc[s0 + c3];
    uint4 q0 = Hq[(size_t)e0 * 16 + fl];
    uint4 q1 = Hq[(size_t)e1 * 16 + fl];
    uint4 q2 = Hq[(size_t)e2 * 16 + fl];
    uint4 q3 = Hq[(size_t)e3 * 16 + fl];
    a0 += u2h(q0.x); a1 += u2h(q0.y); a2 += u2h(q0.z); a3 += u2h(q0.w);
    if (j1 < cnt) { a0 += u2h(q1.x); a1 += u2h(q1.y); a2 += u2h(q1.z); a3 += u2h(q1.w); }
    if (j2 < cnt) { a0 += u2h(q2.x); a1 += u2h(q2.y); a2 += u2h(q2.z); a3 += u2h(q2.w); }
    if (j3 < cnt) { a0 += u2h(q3.x); a1 += u2h(q3.y); a2 += u2h(q3.z); a3 += u2h(q3.w); }
  }
  // to fp32, reduce the 4 edge phases (lanes l, l^16, l^32 hold same features)
  float f0 = (float)a0[0], f1 = (float)a0[1], f2 = (float)a1[0], f3 = (float)a1[1];
  float f4 = (float)a2[0], f5 = (float)a2[1], f6 = (float)a3[0], f7 = (float)a3[1];
  f0 += __shfl_xor(f0, 16); f0 += __shfl_xor(f0, 32);
  f1 += __shfl_xor(f1, 16); f1 += __shfl_xor(f1, 32);
  f2 += __shfl_xor(f2, 16); f2 += __shfl_xor(f2, 32);
  f3 += __shfl_xor(f3, 16); f3 += __shfl_xor(f3, 32);
  f4 += __shfl_xor(f4, 16); f4 += __shfl_xor(f4, 32);
  f5 += __shfl_xor(f5, 16); f5 += __shfl_xor(f5, 32);
  f6 += __shfl_xor(f6, 16); f6 += __shfl_xor(f6, 32);
  f7 += __shfl_xor(f7, 16); f7 += __shfl_xor(f7, 32);
  // self-loop in fp32
  uint4 qs = Hq[(size_t)v * 16 + fl];
  half2_t s0h = u2h(qs.x), s1h = u2h(qs.y), s2h = u2h(qs.z), s3h = u2h(qs.w);
  f0 += (float)s0h[0]; f1 += (float)s0h[1]; f2 += (float)s1h[0]; f3 += (float)s1h[1];
  f4 += (float)s2h[0]; f5 += (float)s2h[1]; f6 += (float)s3h[0]; f7 += (float)s3h[1];
  float dv = dinv[v];
  float4 ba = *(const float4*)&bias[fl * 8];
  float4 bb = *(const float4*)&bias[fl * 8 + 4];
  f0 = f0 * dv + ba.x; f1 = f1 * dv + ba.y; f2 = f2 * dv + ba.z; f3 = f3 * dv + ba.w;
  f4 = f4 * dv + bb.x; f5 = f5 * dv + bb.y; f6 = f6 * dv + bb.z; f7 = f7 * dv + bb.w;
  // LayerNorm stats over 16 octets (values replicated across phases)
  float s  = ((f0 + f1) + (f2 + f3)) + ((f4 + f5) + (f6 + f7));
  float ss = ((f0 * f0 + f1 * f1) + (f2 * f2 + f3 * f3))
           + ((f4 * f4 + f5 * f5) + (f6 * f6 + f7 * f7));
  #pragma unroll
  for (int o = 1; o < 16; o <<= 1) { s += __shfl_xor(s, o); ss += __shfl_xor(ss, o); }
  float mu = s * (1.f / 128.f);
  float var = ss * (1.f / 128.f) - mu * mu;
  float rs = rsqrtf(var + 1e-5f);
  // phase g writes features fl*8 + 2g, 2g+1
  float pa = (g == 0) ? f0 : (g == 1) ? f2 : (g == 2) ? f4 : f6;
  float pb = (g == 0) ? f1 : (g == 1) ? f3 : (g == 2) ? f5 : f7;
  int fi = fl * 8 + g * 2;
  float2 g2 = *(const float2*)&gamma[fi];
  float2 e2 = *(const float2*)&beta[fi];
  float y0 = fmaxf((pa - mu) * rs * g2.x + e2.x, 0.f);
  float y1 = fmaxf((pb - mu) * rs * g2.y + e2.y, 0.f);
  half2_t* Ap = &Ah[(size_t)v * 64 + (fi >> 1)];
  if (res) { half2_t o2 = *Ap; y0 += (float)o2[0]; y1 += (float)o2[1]; }
  half2_t w; w[0] = (half_t)y0; w[1] = (half_t)y1;
  *Ap = w;
}

// ---------------- Global mean pool (batch is sorted, Ah fp16) ----------------
__global__ __launch_bounds__(64) void k_pool(const half2_t* __restrict__ Ah,
                                             const int* __restrict__ batch,
                                             float* __restrict__ sums) {
  const int CH = 64;
  int b0 = blockIdx.x * CH;
  int t = threadIdx.x;  // 64
  int nmax = NN - b0; if (nmax > CH) nmax = CH;
  __shared__ int bb[CH];
  bb[t] = (b0 + t < NN) ? batch[b0 + t] : -1;
  __syncthreads();
  int gfirst = bb[0], glast = bb[nmax - 1];
  if (gfirst == glast) {
    float p0 = 0.f, p1 = 0.f, q0 = 0.f, q1 = 0.f, r0 = 0.f, r1 = 0.f, u0 = 0.f, u1 = 0.f;
    int i = 0;
    for (; i + 4 <= nmax; i += 4) {
      half2_t h0 = Ah[(size_t)(b0 + i + 0) * 64 + t];
      half2_t h1 = Ah[(size_t)(b0 + i + 1) * 64 + t];
      half2_t h2 = Ah[(size_t)(b0 + i + 2) * 64 + t];
      half2_t h3 = Ah[(size_t)(b0 + i + 3) * 64 + t];
      p0 += (float)h0[0]; p1 += (float)h0[1];
      q0 += (float)h1[0]; q1 += (float)h1[1];
      r0 += (float)h2[0]; r1 += (float)h2[1];
      u0 += (float)h3[0]; u1 += (float)h3[1];
    }
    for (; i < nmax; ++i) {
      half2_t h = Ah[(size_t)(b0 + i) * 64 + t];
      p0 += (float)h[0]; p1 += (float)h[1];
    }
    atomicAdd(&sums[gfirst * DIM + 2 * t], (p0 + q0) + (r0 + u0));
    atomicAdd(&sums[gfirst * DIM + 2 * t + 1], (p1 + q1) + (r1 + u1));
  } else {
    float s0 = 0.f, s1 = 0.f;
    int cur = gfirst;
    for (int i = 0; i < nmax; i++) {
      int g = bb[i];
      if (g != cur) {
        atomicAdd(&sums[cur * DIM + 2 * t], s0);
        atomicAdd(&sums[cur * DIM + 2 * t + 1], s1);
        s0 = s1 = 0.f; cur = g;
      }
      half2_t h = Ah[(size_t)(b0 + i) * 64 + t];
      s0 += (float)h[0]; s1 += (float)h[1];
    }
    atomicAdd(&sums[cur * DIM + 2 * t], s0);
    atomicAdd(&sums[cur * DIM + 2 * t + 1], s1);
  }
}

__global__ void k_cnts(const int* __restrict__ batch, float* __restrict__ cnts) {
  int g = threadIdx.x;  // 128
  int lo = 0, hi = NN;
  while (lo < hi) { int mid = (lo + hi) >> 1; if (batch[mid] < g) lo = mid + 1; else hi = mid; }
  int a = lo;
  lo = 0; hi = NN;
  while (lo < hi) { int mid = (lo + hi) >> 1; if (batch[mid] < g + 1) lo = mid + 1; else hi = mid; }
  cnts[g] = (float)(lo - a);
}

// ---------------- Head ----------------
__global__ void k_head(const float* __restrict__ sums, const float* __restrict__ cnts,
                       const float* __restrict__ W1, const float* __restrict__ b1,
                       const float* __restrict__ W2, const float* __restrict__ b2,
                       float* __restrict__ out) {
  int g = blockIdx.x, t = threadIdx.x;  // 64
  __shared__ float p[128];
  float ic = 1.f / fmaxf(cnts[g], 1.f);
  p[t] = sums[g * DIM + t] * ic;
  p[t + 64] = sums[g * DIM + 64 + t] * ic;
  __syncthreads();
  float z = b1[t];
  #pragma unroll 8
  for (int k = 0; k < 128; k++) z += p[k] * W1[k * FCD + t];
  z = fmaxf(z, 0.f);
  float sv = z * W2[t];
  #pragma unroll
  for (int o = 1; o < 64; o <<= 1) sv += __shfl_xor(sv, o);
  if (t == 0) out[g] = 1.f / (1.f + expf(-(sv + b2[0])));
}

extern "C" void kernel_launch(void* const* d_in, const int* in_sizes, int n_in,
                              void* d_out, int out_size, void* d_ws, size_t ws_size,
                              hipStream_t stream) {
  (void)in_sizes; (void)n_in; (void)out_size; (void)ws_size;
  const float* x     = (const float*)d_in[0];
  const int*   ei    = (const int*)d_in[1];
  const int*   batch = (const int*)d_in[2];
  const float* W_in  = (const float*)d_in[3];
  const float* b_in  = (const float*)d_in[4];
  const float* g_in  = (const float*)d_in[5];
  const float* be_in = (const float*)d_in[6];
  const float* W_mid = (const float*)d_in[7];
  const float* b_mid = (const float*)d_in[8];
  const float* g_mid = (const float*)d_in[9];
  const float* be_mid= (const float*)d_in[10];
  const float* W_out = (const float*)d_in[11];
  const float* b_out = (const float*)d_in[12];
  const float* g_out = (const float*)d_in[13];
  const float* be_out= (const float*)d_in[14];
  const float* W1    = (const float*)d_in[15];
  const float* b1    = (const float*)d_in[16];
  const float* W2    = (const float*)d_in[17];
  const float* b2    = (const float*)d_in[18];
  float* out = (float*)d_out;

  // workspace layout (~95 MB)
  char* p = (char*)d_ws;
  auto alloc = [&](size_t bytes) {
    char* r = p;
    p += (bytes + 255) & ~(size_t)255;
    return r;
  };
  half_t* Ah     = (half_t*)alloc((size_t)NN * DIM * 2);  // node features (fp16, sole copy)
  half_t* Xh     = (half_t*)alloc((size_t)NN * DIM * 2);  // input x (fp16)
  half_t* Bh     = (half_t*)alloc((size_t)NN * DIM * 2);  // scaled linear output (fp16)
  float*  dinv   = (float*)alloc((size_t)NN * 4);
  int*    rowptr = (int*)alloc((size_t)(NN + 1) * 4);
  int*    csrc   = (int*)alloc((size_t)NE * 4);
  int*    staged = (int*)alloc((size_t)NCH * ECH * 4);
  int*    offmat = (int*)alloc((size_t)NCH * (NBK + 1) * 4);
  int*    gtot   = (int*)alloc((size_t)(NBK + 1) * 4);
  int*    gbase  = (int*)alloc((size_t)(NBK + 1) * 4);
  float*  sums   = (float*)alloc((size_t)NGRAPH * DIM * 4);
  float*  cnts   = (float*)alloc((size_t)NGRAPH * 4);

  const int* rowp = ei;        // sources
  const int* colp = ei + NE;   // targets

  hipMemsetAsync(gtot, 0, (size_t)(NBK + 1) * 4, stream);
  hipMemsetAsync(sums, 0, (size_t)NGRAPH * DIM * 4, stream);

  k_bucketA<<<NCH, 256, 0, stream>>>(rowp, colp, staged, offmat, gtot);
  k_bsum<<<1, 256, 0, stream>>>(gtot, gbase, rowptr);
  k_csrB<<<NBK, 256, 0, stream>>>(staged, offmat, gbase, rowptr, dinv, csrc);
  k_cvt<<<(NN * DIM / 4 + 255) / 256, 256, 0, stream>>>(x, Xh);

  int gemm_grid = (NN + 63) / 64;
  for (int l = 0; l < 8; l++) {
    const float *Wl, *bl, *gl, *bel;
    if (l == 0)      { Wl = W_in;  bl = b_in;  gl = g_in;  bel = be_in;  }
    else if (l == 7) { Wl = W_out; bl = b_out; gl = g_out; bel = be_out; }
    else             { Wl = W_mid; bl = b_mid; gl = g_mid; bel = be_mid; }
    const half_t* in = (l == 0) ? Xh : Ah;
    k_gemm<<<gemm_grid, 256, 0, stream>>>(in, Wl, dinv, Bh);
    int res = (l >= 2 && l <= 6 && (l % 2 == 0)) ? 1 : 0;
    k_agg<<<NN / 4, 256, 0, stream>>>((const half2_t*)Bh, (half2_t*)Ah,
                                      rowptr, csrc, dinv, bl, gl, bel, res);
  }

  k_pool<<<(NN + 63) / 64, 64, 0, stream>>>((const half2_t*)Ah, batch, sums);
  k_cnts<<<1, 128, 0, stream>>>(batch, cnts);
  k_head<<<NGRAPH, 64, 0, stream>>>(sums, cnts, W1, b1, W2, b2, out);
}

// Round 12
// 760.460 us; speedup vs baseline: 2.0185x; 1.2241x over previous
//
#include <hip/hip_runtime.h>
#include <hip/hip_fp16.h>

#define NN 100000
#define NE 1600000
#define DIM 128
#define NGRAPH 128
#define FCD 64

#define NBK 391          // buckets of 256 target nodes: (NN+255)>>8
#define ECH 8192         // edges per pass-A chunk
#define NCH 196          // (NE + ECH - 1) / ECH
#define ECAP 8192        // pass-B per-bucket LDS capacity (avg ~4092, max ~4400)

typedef _Float16 half_t;
typedef _Float16 half2_t __attribute__((ext_vector_type(2)));
typedef _Float16 half4_t __attribute__((ext_vector_type(4)));
typedef _Float16 half8_t __attribute__((ext_vector_type(8)));
typedef float float4_t __attribute__((ext_vector_type(4)));

__device__ inline half2_t u2h(unsigned u) { union { unsigned u; half2_t h; } x; x.u = u; return x.h; }
__device__ inline unsigned h2u(half2_t h) { union { unsigned u; half2_t h; } x; x.h = h; return x.u; }
__device__ inline half8_t q2h8(uint4 q) { union { uint4 q; half8_t h; } x; x.q = q; return x.h; }

// ---------------- CSR build: two-level counting sort ----------------
__global__ __launch_bounds__(256) void k_bucketA(const int* __restrict__ row,
                                                 const int* __restrict__ col,
                                                 int* __restrict__ staged,
                                                 int* __restrict__ offmat,
                                                 int* __restrict__ gtot) {
  __shared__ int hist[NBK];
  __shared__ int sc[512];
  __shared__ int off[NBK + 1];
  __shared__ int fill[NBK];
  int b = blockIdx.x, t = threadIdx.x;
  int e0 = b * ECH;
  int n = NE - e0; if (n > ECH) n = ECH;
  for (int j = t; j < NBK; j += 256) { hist[j] = 0; fill[j] = 0; }
  __syncthreads();
  for (int i = t; i < n; i += 256) atomicAdd(&hist[col[e0 + i] >> 8], 1);
  __syncthreads();
  sc[t] = (t < NBK) ? hist[t] : 0;
  sc[t + 256] = (t + 256 < NBK) ? hist[t + 256] : 0;
  __syncthreads();
  #pragma unroll
  for (int o = 1; o < 512; o <<= 1) {
    int a0 = (t >= o) ? sc[t - o] : 0;
    int a1 = (t + 256 >= o) ? sc[t + 256 - o] : 0;
    __syncthreads();
    sc[t] += a0; sc[t + 256] += a1;
    __syncthreads();
  }
  if (t == 0) off[0] = 0;
  for (int j = t; j < NBK; j += 256) off[j + 1] = sc[j];
  for (int j = t; j < NBK; j += 256) if (hist[j]) atomicAdd(&gtot[j], hist[j]);
  __syncthreads();
  for (int j = t; j < NBK + 1; j += 256) offmat[b * (NBK + 1) + j] = off[j];
  for (int i = t; i < n; i += 256) {
    int c = col[e0 + i], r = row[e0 + i];
    int bkt = c >> 8;
    int pos = off[bkt] + atomicAdd(&fill[bkt], 1);
    staged[e0 + pos] = (r << 8) | (c & 255);
  }
}

__global__ void k_bsum(const int* __restrict__ gtot, int* __restrict__ gbase,
                       int* __restrict__ rowptr) {
  __shared__ int sc[512];
  int t = threadIdx.x;  // 256
  sc[t] = (t < NBK) ? gtot[t] : 0;
  sc[t + 256] = (t + 256 < NBK) ? gtot[t + 256] : 0;
  __syncthreads();
  #pragma unroll
  for (int o = 1; o < 512; o <<= 1) {
    int a0 = (t >= o) ? sc[t - o] : 0;
    int a1 = (t + 256 >= o) ? sc[t + 256 - o] : 0;
    __syncthreads();
    sc[t] += a0; sc[t + 256] += a1;
    __syncthreads();
  }
  if (t == 0) { gbase[0] = 0; rowptr[NN] = NE; }
  for (int j = t; j < NBK; j += 256) gbase[j + 1] = sc[j];
}

__global__ __launch_bounds__(256) void k_csrB(const int* __restrict__ staged,
                                              const int* __restrict__ offmat,
                                              const int* __restrict__ gbase,
                                              int* __restrict__ rowptr,
                                              float* __restrict__ dinv,
                                              int* __restrict__ csrc) {
  __shared__ int pay[ECAP];
  __shared__ int csn[256];
  __shared__ int nhist[256];
  __shared__ int nscan[256];
  __shared__ int nb[256];
  __shared__ int nfill[256];
  int bkt = blockIdx.x, t = threadIdx.x;
  int gb = gbase[bkt];
  int off = 0, cnt = 0;
  if (t < NCH) {
    int base = t * (NBK + 1) + bkt;
    off = offmat[base];
    cnt = offmat[base + 1] - off;
  }
  csn[t] = cnt;
  __syncthreads();
  #pragma unroll
  for (int o = 1; o < 256; o <<= 1) {
    int a = (t >= o) ? csn[t - o] : 0;
    __syncthreads();
    csn[t] += a;
    __syncthreads();
  }
  int lb = csn[t] - cnt;
  int total = csn[255];
  if (t < NCH) {
    const int* src = staged + t * ECH + off;
    for (int i = 0; i < cnt; i++) pay[lb + i] = src[i];
  }
  nhist[t] = 0; nfill[t] = 0;
  __syncthreads();
  for (int i = t; i < total; i += 256) atomicAdd(&nhist[pay[i] & 255], 1);
  __syncthreads();
  nscan[t] = nhist[t];
  __syncthreads();
  #pragma unroll
  for (int o = 1; o < 256; o <<= 1) {
    int a = (t >= o) ? nscan[t - o] : 0;
    __syncthreads();
    nscan[t] += a;
    __syncthreads();
  }
  nb[t] = nscan[t] - nhist[t];
  int v = bkt * 256 + t;
  if (v < NN) {
    rowptr[v] = gb + nb[t];
    dinv[v] = rsqrtf((float)(nhist[t] + 1));   // +1 self loop
  }
  __syncthreads();
  for (int i = t; i < total; i += 256) {
    int p = pay[i];
    int cl = p & 255;
    int pos = nb[cl] + atomicAdd(&nfill[cl], 1);
    csrc[gb + pos] = p >> 8;
  }
}

// ---------------- x fp32 -> fp16 (layer-0 input only) ----------------
__global__ void k_cvt(const float* __restrict__ x, half_t* __restrict__ Xh) {
  int i = blockIdx.x * 256 + threadIdx.x;
  if ((size_t)i * 4 < (size_t)NN * DIM) {
    float4 v = *(const float4*)&x[(size_t)i * 4];
    half4_t h; h[0] = (half_t)v.x; h[1] = (half_t)v.y; h[2] = (half_t)v.z; h[3] = (half_t)v.w;
    *(half4_t*)&Xh[(size_t)i * 4] = h;
  }
}

// ---------------- W fp32 [k][j] -> Wt fp16 [j][k] (once per weight) ----------------
__global__ void k_wt(const float* __restrict__ W, half_t* __restrict__ Wt) {
  int e = blockIdx.x * 256 + threadIdx.x;   // 16384 entries
  if (e < DIM * DIM) {
    int j = e >> 7, k = e & 127;
    Wt[e] = (half_t)W[k * DIM + j];
  }
}

// ---------------- GEMM via MFMA f16: O[n][j] = dinv[n]*sum_k X[n][k]*Wt[j][k] ----
// mfma_f32_16x16x32_f16. A: lane l holds X[n0+(l&15)][32s+(l>>4)*8+i] (uint4 from
// global). B: lane l holds Wt[jt*16+(l&15)][32s+(l>>4)*8+i] (b128 from LDS).
// C/D: col=lane&15, row=(lane>>4)*4+reg (m89-verified, dtype-independent).
// Block = 4 waves x 2 tiles of 16 rows = 128 rows. Wt staged once (pad 132 halfs).
#define WT_DW 66   // dwords per j-row in LDS (132 halfs)
__global__ __launch_bounds__(256) void k_gemm(const half_t* __restrict__ X,
                                              const uint4* __restrict__ Wtg,
                                              const float* __restrict__ dinv,
                                              half_t* __restrict__ O) {
  __shared__ unsigned wt[DIM * WT_DW];          // 33792 B
  __shared__ half_t outs[4][16 * 136];          // 4 KB per wave
  int t = threadIdx.x;
  int w = t >> 6, l = t & 63;
  // stage Wt (fp16 [j][k]) -> padded LDS
  #pragma unroll
  for (int i = 0; i < 8; i++) {
    int e = t + i * 256;          // 0..2047 uint4
    int j = e >> 4, seg = e & 15;
    *(uint4*)&wt[j * WT_DW + seg * 4] = Wtg[e];
  }
  __syncthreads();
  int lr = l & 15, lk = l >> 4;   // row-in-tile / k-block
  #pragma unroll
  for (int t4 = 0; t4 < 2; t4++) {
    int n0w = blockIdx.x * 128 + w * 32 + t4 * 16;
    int nA = n0w + lr;
    // A fragments: full 256B row in 4 uint4
    uint4 a0 = make_uint4(0,0,0,0), a1 = a0, a2 = a0, a3 = a0;
    if (nA < NN) {
      const uint4* Xq = (const uint4*)&X[(size_t)nA * DIM];
      a0 = Xq[lk];  a1 = Xq[4 + lk];  a2 = Xq[8 + lk];  a3 = Xq[12 + lk];
    }
    float4_t acc[8] = {};
    #pragma unroll
    for (int jt = 0; jt < 8; jt++) {
      int bbase = (jt * 16 + lr) * WT_DW + lk * 4;
      uint4 b0 = *(const uint4*)&wt[bbase];
      uint4 b1 = *(const uint4*)&wt[bbase + 16];
      uint4 b2 = *(const uint4*)&wt[bbase + 32];
      uint4 b3 = *(const uint4*)&wt[bbase + 48];
      acc[jt] = __builtin_amdgcn_mfma_f32_16x16x32_f16(q2h8(a0), q2h8(b0), acc[jt], 0, 0, 0);
      acc[jt] = __builtin_amdgcn_mfma_f32_16x16x32_f16(q2h8(a1), q2h8(b1), acc[jt], 0, 0, 0);
      acc[jt] = __builtin_amdgcn_mfma_f32_16x16x32_f16(q2h8(a2), q2h8(b2), acc[jt], 0, 0, 0);
      acc[jt] = __builtin_amdgcn_mfma_f32_16x16x32_f16(q2h8(a3), q2h8(b3), acc[jt], 0, 0, 0);
    }
    // epilogue: dinv scale, transpose through per-wave LDS, coalesced store
    float dv0 = dinv[min(n0w + lk * 4 + 0, NN - 1)];
    float dv1 = dinv[min(n0w + lk * 4 + 1, NN - 1)];
    float dv2 = dinv[min(n0w + lk * 4 + 2, NN - 1)];
    float dv3 = dinv[min(n0w + lk * 4 + 3, NN - 1)];
    #pragma unroll
    for (int jt = 0; jt < 8; jt++) {
      int cb = jt * 16 + lr;
      outs[w][(lk * 4 + 0) * 136 + cb] = (half_t)(acc[jt][0] * dv0);
      outs[w][(lk * 4 + 1) * 136 + cb] = (half_t)(acc[jt][1] * dv1);
      outs[w][(lk * 4 + 2) * 136 + cb] = (half_t)(acc[jt][2] * dv2);
      outs[w][(lk * 4 + 3) * 136 + cb] = (half_t)(acc[jt][3] * dv3);
    }
    #pragma unroll
    for (int q = 0; q < 4; q++) {
      int idx = l * 4 + q;            // 0..255
      int row = idx >> 4, seg = idx & 15;
      int n = n0w + row;
      if (n < NN) {
        uint4 o4 = *(const uint4*)&outs[w][row * 136 + seg * 8];
        *(uint4*)&O[(size_t)n * DIM + seg * 8] = o4;
      }
    }
  }
}

// ---------------- Aggregation + bias + LayerNorm + ReLU + residual ----------------
// one wave per node; lane = 16-lane group g (edge phase 0..3) x feature octet fl.
// 16 edges in flight per iteration (4 index loads + 4 dwordx4 gathers).
__global__ __launch_bounds__(256) void k_agg(const half2_t* __restrict__ Hh,
                      half2_t* __restrict__ Ah,
                      const int* __restrict__ rowptr, const int* __restrict__ csrc,
                      const float* __restrict__ dinv,
                      const float* __restrict__ bias, const float* __restrict__ gamma,
                      const float* __restrict__ beta, int res) {
  int tid = threadIdx.x;
  int lane = tid & 63;
  int v = blockIdx.x * 4 + (tid >> 6);   // one node per wave; NN % 4 == 0
  int g = lane >> 4;                     // edge phase 0..3
  int fl = lane & 15;                    // feature octet 0..15 (8 halfs)
  int s0 = rowptr[v];
  int cnt = rowptr[v + 1] - s0;
  const uint4* Hq = (const uint4*)Hh;    // 16 uint4 per 128-half row
  half2_t a0 = u2h(0u), a1 = u2h(0u), a2 = u2h(0u), a3 = u2h(0u);
  for (int i = g; i < cnt; i += 16) {    // phases i, i+4, i+8, i+12
    int j1 = i + 4, j2 = i + 8, j3 = i + 12;
    int c1 = min(j1, cnt - 1);
    int c2 = min(j2, cnt - 1);
    int c3 = min(j3, cnt - 1);
    int e0 = csrc[s0 + i];
    int e1 = csrc[s0 + c1];
    int e2 = csrc[s0 + c2];
    int e3 = csrc[s0 + c3];
    uint4 q0 = Hq[(size_t)e0 * 16 + fl];
    uint4 q1 = Hq[(size_t)e1 * 16 + fl];
    uint4 q2 = Hq[(size_t)e2 * 16 + fl];
    uint4 q3 = Hq[(size_t)e3 * 16 + fl];
    a0 += u2h(q0.x); a1 += u2h(q0.y); a2 += u2h(q0.z); a3 += u2h(q0.w);
    if (j1 < cnt) { a0 += u2h(q1.x); a1 += u2h(q1.y); a2 += u2h(q1.z); a3 += u2h(q1.w); }
    if (j2 < cnt) { a0 += u2h(q2.x); a1 += u2h(q2.y); a2 += u2h(q2.z); a3 += u2h(q2.w); }
    if (j3 < cnt) { a0 += u2h(q3.x); a1 += u2h(q3.y); a2 += u2h(q3.z); a3 += u2h(q3.w); }
  }
  // to fp32, reduce the 4 edge phases (lanes l, l^16, l^32 hold same features)
  float f0 = (float)a0[0], f1 = (float)a0[1], f2 = (float)a1[0], f3 = (float)a1[1];
  float f4 = (float)a2[0], f5 = (float)a2[1], f6 = (float)a3[0], f7 = (float)a3[1];
  f0 += __shfl_xor(f0, 16); f0 += __shfl_xor(f0, 32);
  f1 += __shfl_xor(f1, 16); f1 += __shfl_xor(f1, 32);
  f2 += __shfl_xor(f2, 16); f2 += __shfl_xor(f2, 32);
  f3 += __shfl_xor(f3, 16); f3 += __shfl_xor(f3, 32);
  f4 += __shfl_xor(f4, 16); f4 += __shfl_xor(f4, 32);
  f5 += __shfl_xor(f5, 16); f5 += __shfl_xor(f5, 32);
  f6 += __shfl_xor(f6, 16); f6 += __shfl_xor(f6, 32);
  f7 += __shfl_xor(f7, 16); f7 += __shfl_xor(f7, 32);
  // self-loop in fp32
  uint4 qs = Hq[(size_t)v * 16 + fl];
  half2_t s0h = u2h(qs.x), s1h = u2h(qs.y), s2h = u2h(qs.z), s3h = u2h(qs.w);
  f0 += (float)s0h[0]; f1 += (float)s0h[1]; f2 += (float)s1h[0]; f3 += (float)s1h[1];
  f4 += (float)s2h[0]; f5 += (float)s2h[1]; f6 += (float)s3h[0]; f7 += (float)s3h[1];
  float dv = dinv[v];
  float4 ba = *(const float4*)&bias[fl * 8];
  float4 bb = *(const float4*)&bias[fl * 8 + 4];
  f0 = f0 * dv + ba.x; f1 = f1 * dv + ba.y; f2 = f2 * dv + ba.z; f3 = f3 * dv + ba.w;
  f4 = f4 * dv + bb.x; f5 = f5 * dv + bb.y; f6 = f6 * dv + bb.z; f7 = f7 * dv + bb.w;
  // LayerNorm stats over 16 octets (values replicated across phases)
  float s  = ((f0 + f1) + (f2 + f3)) + ((f4 + f5) + (f6 + f7));
  float ss = ((f0 * f0 + f1 * f1) + (f2 * f2 + f3 * f3))
           + ((f4 * f4 + f5 * f5) + (f6 * f6 + f7 * f7));
  #pragma unroll
  for (int o = 1; o < 16; o <<= 1) { s += __shfl_xor(s, o); ss += __shfl_xor(ss, o); }
  float mu = s * (1.f / 128.f);
  float var = ss * (1.f / 128.f) - mu * mu;
  float rs = rsqrtf(var + 1e-5f);
  // phase g writes features fl*8 + 2g, 2g+1
  float pa = (g == 0) ? f0 : (g == 1) ? f2 : (g == 2) ? f4 : f6;
  float pb = (g == 0) ? f1 : (g == 1) ? f3 : (g == 2) ? f5 : f7;
  int fi = fl * 8 + g * 2;
  float2 g2 = *(const float2*)&gamma[fi];
  float2 e2 = *(const float2*)&beta[fi];
  float y0 = fmaxf((pa - mu) * rs * g2.x + e2.x, 0.f);
  float y1 = fmaxf((pb - mu) * rs * g2.y + e2.y, 0.f);
  half2_t* Ap = &Ah[(size_t)v * 64 + (fi >> 1)];
  if (res) { half2_t o2 = *Ap; y0 += (float)o2[0]; y1 += (float)o2[1]; }
  half2_t w; w[0] = (half_t)y0; w[1] = (half_t)y1;
  *Ap = w;
}

// ---------------- Global mean pool (batch is sorted, Ah fp16) ----------------
__global__ __launch_bounds__(64) void k_pool(const half2_t* __restrict__ Ah,
                                             const int* __restrict__ batch,
                                             float* __restrict__ sums) {
  const int CH = 64;
  int b0 = blockIdx.x * CH;
  int t = threadIdx.x;  // 64
  int nmax = NN - b0; if (nmax > CH) nmax = CH;
  __shared__ int bb[CH];
  bb[t] = (b0 + t < NN) ? batch[b0 + t] : -1;
  __syncthreads();
  int gfirst = bb[0], glast = bb[nmax - 1];
  if (gfirst == glast) {
    float p0 = 0.f, p1 = 0.f, q0 = 0.f, q1 = 0.f, r0 = 0.f, r1 = 0.f, u0 = 0.f, u1 = 0.f;
    int i = 0;
    for (; i + 4 <= nmax; i += 4) {
      half2_t h0 = Ah[(size_t)(b0 + i + 0) * 64 + t];
      half2_t h1 = Ah[(size_t)(b0 + i + 1) * 64 + t];
      half2_t h2 = Ah[(size_t)(b0 + i + 2) * 64 + t];
      half2_t h3 = Ah[(size_t)(b0 + i + 3) * 64 + t];
      p0 += (float)h0[0]; p1 += (float)h0[1];
      q0 += (float)h1[0]; q1 += (float)h1[1];
      r0 += (float)h2[0]; r1 += (float)h2[1];
      u0 += (float)h3[0]; u1 += (float)h3[1];
    }
    for (; i < nmax; ++i) {
      half2_t h = Ah[(size_t)(b0 + i) * 64 + t];
      p0 += (float)h[0]; p1 += (float)h[1];
    }
    atomicAdd(&sums[gfirst * DIM + 2 * t], (p0 + q0) + (r0 + u0));
    atomicAdd(&sums[gfirst * DIM + 2 * t + 1], (p1 + q1) + (r1 + u1));
  } else {
    float s0 = 0.f, s1 = 0.f;
    int cur = gfirst;
    for (int i = 0; i < nmax; i++) {
      int g = bb[i];
      if (g != cur) {
        atomicAdd(&sums[cur * DIM + 2 * t], s0);
        atomicAdd(&sums[cur * DIM + 2 * t + 1], s1);
        s0 = s1 = 0.f; cur = g;
      }
      half2_t h = Ah[(size_t)(b0 + i) * 64 + t];
      s0 += (float)h[0]; s1 += (float)h[1];
    }
    atomicAdd(&sums[cur * DIM + 2 * t], s0);
    atomicAdd(&sums[cur * DIM + 2 * t + 1], s1);
  }
}

__global__ void k_cnts(const int* __restrict__ batch, float* __restrict__ cnts) {
  int g = threadIdx.x;  // 128
  int lo = 0, hi = NN;
  while (lo < hi) { int mid = (lo + hi) >> 1; if (batch[mid] < g) lo = mid + 1; else hi = mid; }
  int a = lo;
  lo = 0; hi = NN;
  while (lo < hi) { int mid = (lo + hi) >> 1; if (batch[mid] < g + 1) lo = mid + 1; else hi = mid; }
  cnts[g] = (float)(lo - a);
}

// ---------------- Head ----------------
__global__ void k_head(const float* __restrict__ sums, const float* __restrict__ cnts,
                       const float* __restrict__ W1, const float* __restrict__ b1,
                       const float* __restrict__ W2, const float* __restrict__ b2,
                       float* __restrict__ out) {
  int g = blockIdx.x, t = threadIdx.x;  // 64
  __shared__ float p[128];
  float ic = 1.f / fmaxf(cnts[g], 1.f);
  p[t] = sums[g * DIM + t] * ic;
  p[t + 64] = sums[g * DIM + 64 + t] * ic;
  __syncthreads();
  float z = b1[t];
  #pragma unroll 8
  for (int k = 0; k < 128; k++) z += p[k] * W1[k * FCD + t];
  z = fmaxf(z, 0.f);
  float sv = z * W2[t];
  #pragma unroll
  for (int o = 1; o < 64; o <<= 1) sv += __shfl_xor(sv, o);
  if (t == 0) out[g] = 1.f / (1.f + expf(-(sv + b2[0])));
}

extern "C" void kernel_launch(void* const* d_in, const int* in_sizes, int n_in,
                              void* d_out, int out_size, void* d_ws, size_t ws_size,
                              hipStream_t stream) {
  (void)in_sizes; (void)n_in; (void)out_size; (void)ws_size;
  const float* x     = (const float*)d_in[0];
  const int*   ei    = (const int*)d_in[1];
  const int*   batch = (const int*)d_in[2];
  const float* W_in  = (const float*)d_in[3];
  const float* b_in  = (const float*)d_in[4];
  const float* g_in  = (const float*)d_in[5];
  const float* be_in = (const float*)d_in[6];
  const float* W_mid = (const float*)d_in[7];
  const float* b_mid = (const float*)d_in[8];
  const float* g_mid = (const float*)d_in[9];
  const float* be_mid= (const float*)d_in[10];
  const float* W_out = (const float*)d_in[11];
  const float* b_out = (const float*)d_in[12];
  const float* g_out = (const float*)d_in[13];
  const float* be_out= (const float*)d_in[14];
  const float* W1    = (const float*)d_in[15];
  const float* b1    = (const float*)d_in[16];
  const float* W2    = (const float*)d_in[17];
  const float* b2    = (const float*)d_in[18];
  float* out = (float*)d_out;

  // workspace layout (~95 MB)
  char* p = (char*)d_ws;
  auto alloc = [&](size_t bytes) {
    char* r = p;
    p += (bytes + 255) & ~(size_t)255;
    return r;
  };
  half_t* Ah     = (half_t*)alloc((size_t)NN * DIM * 2);  // node features (fp16, sole copy)
  half_t* Xh     = (half_t*)alloc((size_t)NN * DIM * 2);  // input x (fp16)
  half_t* Bh     = (half_t*)alloc((size_t)NN * DIM * 2);  // scaled linear output (fp16)
  half_t* Wt3    = (half_t*)alloc((size_t)3 * DIM * DIM * 2); // transposed fp16 weights
  float*  dinv   = (float*)alloc((size_t)NN * 4);
  int*    rowptr = (int*)alloc((size_t)(NN + 1) * 4);
  int*    csrc   = (int*)alloc((size_t)NE * 4);
  int*    staged = (int*)alloc((size_t)NCH * ECH * 4);
  int*    offmat = (int*)alloc((size_t)NCH * (NBK + 1) * 4);
  int*    gtot   = (int*)alloc((size_t)(NBK + 1) * 4);
  int*    gbase  = (int*)alloc((size_t)(NBK + 1) * 4);
  float*  sums   = (float*)alloc((size_t)NGRAPH * DIM * 4);
  float*  cnts   = (float*)alloc((size_t)NGRAPH * 4);

  const int* rowp = ei;        // sources
  const int* colp = ei + NE;   // targets

  hipMemsetAsync(gtot, 0, (size_t)(NBK + 1) * 4, stream);
  hipMemsetAsync(sums, 0, (size_t)NGRAPH * DIM * 4, stream);

  k_bucketA<<<NCH, 256, 0, stream>>>(rowp, colp, staged, offmat, gtot);
  k_bsum<<<1, 256, 0, stream>>>(gtot, gbase, rowptr);
  k_csrB<<<NBK, 256, 0, stream>>>(staged, offmat, gbase, rowptr, dinv, csrc);
  k_cvt<<<(NN * DIM / 4 + 255) / 256, 256, 0, stream>>>(x, Xh);
  k_wt<<<(DIM * DIM + 255) / 256, 256, 0, stream>>>(W_in,  Wt3);
  k_wt<<<(DIM * DIM + 255) / 256, 256, 0, stream>>>(W_mid, Wt3 + DIM * DIM);
  k_wt<<<(DIM * DIM + 255) / 256, 256, 0, stream>>>(W_out, Wt3 + 2 * DIM * DIM);

  int gemm_grid = (NN + 127) / 128;   // 782
  for (int l = 0; l < 8; l++) {
    const half_t* Wtl;
    const float *bl, *gl, *bel;
    if (l == 0)      { Wtl = Wt3;                 bl = b_in;  gl = g_in;  bel = be_in;  }
    else if (l == 7) { Wtl = Wt3 + 2 * DIM * DIM; bl = b_out; gl = g_out; bel = be_out; }
    else             { Wtl = Wt3 + DIM * DIM;     bl = b_mid; gl = g_mid; bel = be_mid; }
    const half_t* in = (l == 0) ? Xh : Ah;
    k_gemm<<<gemm_grid, 256, 0, stream>>>(in, (const uint4*)Wtl, dinv, Bh);
    int res = (l >= 2 && l <= 6 && (l % 2 == 0)) ? 1 : 0;
    k_agg<<<NN / 4, 256, 0, stream>>>((const half2_t*)Bh, (half2_t*)Ah,
                                      rowptr, csrc, dinv, bl, gl, bel, res);
  }

  k_pool<<<(NN + 63) / 64, 64, 0, stream>>>((const half2_t*)Ah, batch, sums);
  k_cnts<<<1, 128, 0, stream>>>(batch, cnts);
  k_head<<<NGRAPH, 64, 0, stream>>>(sums, cnts, W1, b1, W2, b2, out);
}

// Round 13
// 758.438 us; speedup vs baseline: 2.0239x; 1.0027x over previous
//
#include <hip/hip_runtime.h>
#include <hip/hip_fp16.h>

#define NN 100000
#define NE 1600000
#define DIM 128
#define NGRAPH 128
#define FCD 64

#define NBK 391          // buckets of 256 target nodes: (NN+255)>>8
#define ECH 8192         // edges per pass-A chunk
#define NCH 196          // (NE + ECH - 1) / ECH
#define ECAP 8192        // pass-B per-bucket LDS capacity (avg ~4092, max ~4400)

typedef _Float16 half_t;
typedef _Float16 half2_t __attribute__((ext_vector_type(2)));
typedef _Float16 half4_t __attribute__((ext_vector_type(4)));
typedef _Float16 half8_t __attribute__((ext_vector_type(8)));
typedef float float4_t __attribute__((ext_vector_type(4)));

__device__ inline half2_t u2h(unsigned u) { union { unsigned u; half2_t h; } x; x.u = u; return x.h; }
__device__ inline unsigned h2u(half2_t h) { union { unsigned u; half2_t h; } x; x.h = h; return x.u; }
__device__ inline half8_t q2h8(uint4 q) { union { uint4 q; half8_t h; } x; x.q = q; return x.h; }

// ---------------- CSR build: two-level counting sort ----------------
__global__ __launch_bounds__(256) void k_bucketA(const int* __restrict__ row,
                                                 const int* __restrict__ col,
                                                 int* __restrict__ staged,
                                                 int* __restrict__ offmat,
                                                 int* __restrict__ gtot) {
  __shared__ int hist[NBK];
  __shared__ int sc[512];
  __shared__ int off[NBK + 1];
  __shared__ int fill[NBK];
  int b = blockIdx.x, t = threadIdx.x;
  int e0 = b * ECH;
  int n = NE - e0; if (n > ECH) n = ECH;
  for (int j = t; j < NBK; j += 256) { hist[j] = 0; fill[j] = 0; }
  __syncthreads();
  for (int i = t; i < n; i += 256) atomicAdd(&hist[col[e0 + i] >> 8], 1);
  __syncthreads();
  sc[t] = (t < NBK) ? hist[t] : 0;
  sc[t + 256] = (t + 256 < NBK) ? hist[t + 256] : 0;
  __syncthreads();
  #pragma unroll
  for (int o = 1; o < 512; o <<= 1) {
    int a0 = (t >= o) ? sc[t - o] : 0;
    int a1 = (t + 256 >= o) ? sc[t + 256 - o] : 0;
    __syncthreads();
    sc[t] += a0; sc[t + 256] += a1;
    __syncthreads();
  }
  if (t == 0) off[0] = 0;
  for (int j = t; j < NBK; j += 256) off[j + 1] = sc[j];
  for (int j = t; j < NBK; j += 256) if (hist[j]) atomicAdd(&gtot[j], hist[j]);
  __syncthreads();
  for (int j = t; j < NBK + 1; j += 256) offmat[b * (NBK + 1) + j] = off[j];
  for (int i = t; i < n; i += 256) {
    int c = col[e0 + i], r = row[e0 + i];
    int bkt = c >> 8;
    int pos = off[bkt] + atomicAdd(&fill[bkt], 1);
    staged[e0 + pos] = (r << 8) | (c & 255);
  }
}

__global__ void k_bsum(const int* __restrict__ gtot, int* __restrict__ gbase,
                       int* __restrict__ rowptr) {
  __shared__ int sc[512];
  int t = threadIdx.x;  // 256
  sc[t] = (t < NBK) ? gtot[t] : 0;
  sc[t + 256] = (t + 256 < NBK) ? gtot[t + 256] : 0;
  __syncthreads();
  #pragma unroll
  for (int o = 1; o < 512; o <<= 1) {
    int a0 = (t >= o) ? sc[t - o] : 0;
    int a1 = (t + 256 >= o) ? sc[t + 256 - o] : 0;
    __syncthreads();
    sc[t] += a0; sc[t + 256] += a1;
    __syncthreads();
  }
  if (t == 0) { gbase[0] = 0; rowptr[NN] = NE; }
  for (int j = t; j < NBK; j += 256) gbase[j + 1] = sc[j];
}

__global__ __launch_bounds__(256) void k_csrB(const int* __restrict__ staged,
                                              const int* __restrict__ offmat,
                                              const int* __restrict__ gbase,
                                              int* __restrict__ rowptr,
                                              float* __restrict__ dinv,
                                              int* __restrict__ csrc) {
  __shared__ int pay[ECAP];
  __shared__ int csn[256];
  __shared__ int nhist[256];
  __shared__ int nscan[256];
  __shared__ int nb[256];
  __shared__ int nfill[256];
  int bkt = blockIdx.x, t = threadIdx.x;
  int gb = gbase[bkt];
  int off = 0, cnt = 0;
  if (t < NCH) {
    int base = t * (NBK + 1) + bkt;
    off = offmat[base];
    cnt = offmat[base + 1] - off;
  }
  csn[t] = cnt;
  __syncthreads();
  #pragma unroll
  for (int o = 1; o < 256; o <<= 1) {
    int a = (t >= o) ? csn[t - o] : 0;
    __syncthreads();
    csn[t] += a;
    __syncthreads();
  }
  int lb = csn[t] - cnt;
  int total = csn[255];
  if (t < NCH) {
    const int* src = staged + t * ECH + off;
    for (int i = 0; i < cnt; i++) pay[lb + i] = src[i];
  }
  nhist[t] = 0; nfill[t] = 0;
  __syncthreads();
  for (int i = t; i < total; i += 256) atomicAdd(&nhist[pay[i] & 255], 1);
  __syncthreads();
  nscan[t] = nhist[t];
  __syncthreads();
  #pragma unroll
  for (int o = 1; o < 256; o <<= 1) {
    int a = (t >= o) ? nscan[t - o] : 0;
    __syncthreads();
    nscan[t] += a;
    __syncthreads();
  }
  nb[t] = nscan[t] - nhist[t];
  int v = bkt * 256 + t;
  if (v < NN) {
    rowptr[v] = gb + nb[t];
    dinv[v] = rsqrtf((float)(nhist[t] + 1));   // +1 self loop
  }
  __syncthreads();
  for (int i = t; i < total; i += 256) {
    int p = pay[i];
    int cl = p & 255;
    int pos = nb[cl] + atomicAdd(&nfill[cl], 1);
    csrc[gb + pos] = p >> 8;
  }
}

// ---------------- x fp32 -> fp16 (layer-0 input only) ----------------
__global__ void k_cvt(const float* __restrict__ x, half_t* __restrict__ Xh) {
  int i = blockIdx.x * 256 + threadIdx.x;
  if ((size_t)i * 4 < (size_t)NN * DIM) {
    float4 v = *(const float4*)&x[(size_t)i * 4];
    half4_t h; h[0] = (half_t)v.x; h[1] = (half_t)v.y; h[2] = (half_t)v.z; h[3] = (half_t)v.w;
    *(half4_t*)&Xh[(size_t)i * 4] = h;
  }
}

// ---------------- W fp32 [k][j] -> Wt fp16 [j][k] (once per weight) ----------------
__global__ void k_wt(const float* __restrict__ W, half_t* __restrict__ Wt) {
  int e = blockIdx.x * 256 + threadIdx.x;   // 16384 entries
  if (e < DIM * DIM) {
    int j = e >> 7, k = e & 127;
    Wt[e] = (half_t)W[k * DIM + j];
  }
}

// ---------------- GEMM via MFMA f16: O[n][j] = dinv[n]*sum_k X[n][k]*Wt[j][k] ----
// mfma_f32_16x16x32_f16. A: lane l holds X[n0+(l&15)][32s+(l>>4)*8+i].
// B: lane l holds Wt[jt*16+(l&15)][32s+(l>>4)*8+i] (b128 from LDS).
// C/D: col=lane&15, row=(lane>>4)*4+reg.
// Block = 4 waves x 2 tiles of 16 rows. Both tiles' A prefetched before the
// staging barrier; B fragments shared across the 2 tiles (ds:MFMA = 1:2).
#define WT_DW 66   // dwords per j-row in LDS (132 halfs)
__global__ __launch_bounds__(256) void k_gemm(const half_t* __restrict__ X,
                                              const uint4* __restrict__ Wtg,
                                              const float* __restrict__ dinv,
                                              half_t* __restrict__ O) {
  __shared__ unsigned wt[DIM * WT_DW];          // 33792 B
  __shared__ half_t outs[4][16 * 136];          // 4.25 KB per wave
  int t = threadIdx.x;
  int w = t >> 6, l = t & 63;
  int lr = l & 15, lk = l >> 4;   // row-in-tile / k-block
  int n0w0 = blockIdx.x * 128 + w * 32;
  int n0w1 = n0w0 + 16;
  // prefetch BOTH tiles' A fragments (global; overlaps Wt staging)
  uint4 z4 = make_uint4(0, 0, 0, 0);
  uint4 a00 = z4, a01 = z4, a02 = z4, a03 = z4;
  uint4 a10 = z4, a11 = z4, a12 = z4, a13 = z4;
  {
    int nA0 = n0w0 + lr;
    if (nA0 < NN) {
      const uint4* Xq = (const uint4*)&X[(size_t)nA0 * DIM];
      a00 = Xq[lk]; a01 = Xq[4 + lk]; a02 = Xq[8 + lk]; a03 = Xq[12 + lk];
    }
    int nA1 = n0w1 + lr;
    if (nA1 < NN) {
      const uint4* Xq = (const uint4*)&X[(size_t)nA1 * DIM];
      a10 = Xq[lk]; a11 = Xq[4 + lk]; a12 = Xq[8 + lk]; a13 = Xq[12 + lk];
    }
  }
  // dinv for both tiles' epilogues
  float dv00 = dinv[min(n0w0 + lk * 4 + 0, NN - 1)];
  float dv01 = dinv[min(n0w0 + lk * 4 + 1, NN - 1)];
  float dv02 = dinv[min(n0w0 + lk * 4 + 2, NN - 1)];
  float dv03 = dinv[min(n0w0 + lk * 4 + 3, NN - 1)];
  float dv10 = dinv[min(n0w1 + lk * 4 + 0, NN - 1)];
  float dv11 = dinv[min(n0w1 + lk * 4 + 1, NN - 1)];
  float dv12 = dinv[min(n0w1 + lk * 4 + 2, NN - 1)];
  float dv13 = dinv[min(n0w1 + lk * 4 + 3, NN - 1)];
  // stage Wt (fp16 [j][k]) -> padded LDS
  #pragma unroll
  for (int i = 0; i < 8; i++) {
    int e = t + i * 256;          // 0..2047 uint4
    int j = e >> 4, seg = e & 15;
    *(uint4*)&wt[j * WT_DW + seg * 4] = Wtg[e];
  }
  __syncthreads();
  float4_t acc0[8] = {};
  float4_t acc1[8] = {};
  #pragma unroll
  for (int jt = 0; jt < 8; jt++) {
    int bbase = (jt * 16 + lr) * WT_DW + lk * 4;
    uint4 b0 = *(const uint4*)&wt[bbase];
    uint4 b1 = *(const uint4*)&wt[bbase + 16];
    uint4 b2 = *(const uint4*)&wt[bbase + 32];
    uint4 b3 = *(const uint4*)&wt[bbase + 48];
    acc0[jt] = __builtin_amdgcn_mfma_f32_16x16x32_f16(q2h8(a00), q2h8(b0), acc0[jt], 0, 0, 0);
    acc0[jt] = __builtin_amdgcn_mfma_f32_16x16x32_f16(q2h8(a01), q2h8(b1), acc0[jt], 0, 0, 0);
    acc0[jt] = __builtin_amdgcn_mfma_f32_16x16x32_f16(q2h8(a02), q2h8(b2), acc0[jt], 0, 0, 0);
    acc0[jt] = __builtin_amdgcn_mfma_f32_16x16x32_f16(q2h8(a03), q2h8(b3), acc0[jt], 0, 0, 0);
    acc1[jt] = __builtin_amdgcn_mfma_f32_16x16x32_f16(q2h8(a10), q2h8(b0), acc1[jt], 0, 0, 0);
    acc1[jt] = __builtin_amdgcn_mfma_f32_16x16x32_f16(q2h8(a11), q2h8(b1), acc1[jt], 0, 0, 0);
    acc1[jt] = __builtin_amdgcn_mfma_f32_16x16x32_f16(q2h8(a12), q2h8(b2), acc1[jt], 0, 0, 0);
    acc1[jt] = __builtin_amdgcn_mfma_f32_16x16x32_f16(q2h8(a13), q2h8(b3), acc1[jt], 0, 0, 0);
  }
  // epilogue tile0: dinv scale, transpose through per-wave LDS, coalesced store
  #pragma unroll
  for (int jt = 0; jt < 8; jt++) {
    int cb = jt * 16 + lr;
    outs[w][(lk * 4 + 0) * 136 + cb] = (half_t)(acc0[jt][0] * dv00);
    outs[w][(lk * 4 + 1) * 136 + cb] = (half_t)(acc0[jt][1] * dv01);
    outs[w][(lk * 4 + 2) * 136 + cb] = (half_t)(acc0[jt][2] * dv02);
    outs[w][(lk * 4 + 3) * 136 + cb] = (half_t)(acc0[jt][3] * dv03);
  }
  #pragma unroll
  for (int q = 0; q < 4; q++) {
    int idx = l * 4 + q;            // 0..255
    int row = idx >> 4, seg = idx & 15;
    int n = n0w0 + row;
    if (n < NN) {
      uint4 o4 = *(const uint4*)&outs[w][row * 136 + seg * 8];
      *(uint4*)&O[(size_t)n * DIM + seg * 8] = o4;
    }
  }
  // epilogue tile1
  #pragma unroll
  for (int jt = 0; jt < 8; jt++) {
    int cb = jt * 16 + lr;
    outs[w][(lk * 4 + 0) * 136 + cb] = (half_t)(acc1[jt][0] * dv10);
    outs[w][(lk * 4 + 1) * 136 + cb] = (half_t)(acc1[jt][1] * dv11);
    outs[w][(lk * 4 + 2) * 136 + cb] = (half_t)(acc1[jt][2] * dv12);
    outs[w][(lk * 4 + 3) * 136 + cb] = (half_t)(acc1[jt][3] * dv13);
  }
  #pragma unroll
  for (int q = 0; q < 4; q++) {
    int idx = l * 4 + q;
    int row = idx >> 4, seg = idx & 15;
    int n = n0w1 + row;
    if (n < NN) {
      uint4 o4 = *(const uint4*)&outs[w][row * 136 + seg * 8];
      *(uint4*)&O[(size_t)n * DIM + seg * 8] = o4;
    }
  }
}

// ---------------- Aggregation + bias + LayerNorm + ReLU + residual ----------------
// one wave per node; lane = 16-lane group g (edge phase 0..3) x feature octet fl.
// 16 edges in flight per iteration (4 index loads + 4 dwordx4 gathers).
__global__ __launch_bounds__(256) void k_agg(const half2_t* __restrict__ Hh,
                      half2_t* __restrict__ Ah,
                      const int* __restrict__ rowptr, const int* __restrict__ csrc,
                      const float* __restrict__ dinv,
                      const float* __restrict__ bias, const float* __restrict__ gamma,
                      const float* __restrict__ beta, int res) {
  int tid = threadIdx.x;
  int lane = tid & 63;
  int v = blockIdx.x * 4 + (tid >> 6);   // one node per wave; NN % 4 == 0
  int g = lane >> 4;                     // edge phase 0..3
  int fl = lane & 15;                    // feature octet 0..15 (8 halfs)
  int s0 = rowptr[v];
  int cnt = rowptr[v + 1] - s0;
  const uint4* Hq = (const uint4*)Hh;    // 16 uint4 per 128-half row
  half2_t a0 = u2h(0u), a1 = u2h(0u), a2 = u2h(0u), a3 = u2h(0u);
  for (int i = g; i < cnt; i += 16) {    // phases i, i+4, i+8, i+12
    int j1 = i + 4, j2 = i + 8, j3 = i + 12;
    int c1 = min(j1, cnt - 1);
    int c2 = min(j2, cnt - 1);
    int c3 = min(j3, cnt - 1);
    int e0 = csrc[s0 + i];
    int e1 = csrc[s0 + c1];
    int e2 = csrc[s0 + c2];
    int e3 = csrc[s0 + c3];
    uint4 q0 = Hq[(size_t)e0 * 16 + fl];
    uint4 q1 = Hq[(size_t)e1 * 16 + fl];
    uint4 q2 = Hq[(size_t)e2 * 16 + fl];
    uint4 q3 = Hq[(size_t)e3 * 16 + fl];
    a0 += u2h(q0.x); a1 += u2h(q0.y); a2 += u2h(q0.z); a3 += u2h(q0.w);
    if (j1 < cnt) { a0 += u2h(q1.x); a1 += u2h(q1.y); a2 += u2h(q1.z); a3 += u2h(q1.w); }
    if (j2 < cnt) { a0 += u2h(q2.x); a1 += u2h(q2.y); a2 += u2h(q2.z); a3 += u2h(q2.w); }
    if (j3 < cnt) { a0 += u2h(q3.x); a1 += u2h(q3.y); a2 += u2h(q3.z); a3 += u2h(q3.w); }
  }
  // to fp32, reduce the 4 edge phases (lanes l, l^16, l^32 hold same features)
  float f0 = (float)a0[0], f1 = (float)a0[1], f2 = (float)a1[0], f3 = (float)a1[1];
  float f4 = (float)a2[0], f5 = (float)a2[1], f6 = (float)a3[0], f7 = (float)a3[1];
  f0 += __shfl_xor(f0, 16); f0 += __shfl_xor(f0, 32);
  f1 += __shfl_xor(f1, 16); f1 += __shfl_xor(f1, 32);
  f2 += __shfl_xor(f2, 16); f2 += __shfl_xor(f2, 32);
  f3 += __shfl_xor(f3, 16); f3 += __shfl_xor(f3, 32);
  f4 += __shfl_xor(f4, 16); f4 += __shfl_xor(f4, 32);
  f5 += __shfl_xor(f5, 16); f5 += __shfl_xor(f5, 32);
  f6 += __shfl_xor(f6, 16); f6 += __shfl_xor(f6, 32);
  f7 += __shfl_xor(f7, 16); f7 += __shfl_xor(f7, 32);
  // self-loop in fp32
  uint4 qs = Hq[(size_t)v * 16 + fl];
  half2_t s0h = u2h(qs.x), s1h = u2h(qs.y), s2h = u2h(qs.z), s3h = u2h(qs.w);
  f0 += (float)s0h[0]; f1 += (float)s0h[1]; f2 += (float)s1h[0]; f3 += (float)s1h[1];
  f4 += (float)s2h[0]; f5 += (float)s2h[1]; f6 += (float)s3h[0]; f7 += (float)s3h[1];
  float dv = dinv[v];
  float4 ba = *(const float4*)&bias[fl * 8];
  float4 bb = *(const float4*)&bias[fl * 8 + 4];
  f0 = f0 * dv + ba.x; f1 = f1 * dv + ba.y; f2 = f2 * dv + ba.z; f3 = f3 * dv + ba.w;
  f4 = f4 * dv + bb.x; f5 = f5 * dv + bb.y; f6 = f6 * dv + bb.z; f7 = f7 * dv + bb.w;
  // LayerNorm stats over 16 octets (values replicated across phases)
  float s  = ((f0 + f1) + (f2 + f3)) + ((f4 + f5) + (f6 + f7));
  float ss = ((f0 * f0 + f1 * f1) + (f2 * f2 + f3 * f3))
           + ((f4 * f4 + f5 * f5) + (f6 * f6 + f7 * f7));
  #pragma unroll
  for (int o = 1; o < 16; o <<= 1) { s += __shfl_xor(s, o); ss += __shfl_xor(ss, o); }
  float mu = s * (1.f / 128.f);
  float var = ss * (1.f / 128.f) - mu * mu;
  float rs = rsqrtf(var + 1e-5f);
  // phase g writes features fl*8 + 2g, 2g+1
  float pa = (g == 0) ? f0 : (g == 1) ? f2 : (g == 2) ? f4 : f6;
  float pb = (g == 0) ? f1 : (g == 1) ? f3 : (g == 2) ? f5 : f7;
  int fi = fl * 8 + g * 2;
  float2 g2 = *(const float2*)&gamma[fi];
  float2 e2 = *(const float2*)&beta[fi];
  float y0 = fmaxf((pa - mu) * rs * g2.x + e2.x, 0.f);
  float y1 = fmaxf((pb - mu) * rs * g2.y + e2.y, 0.f);
  half2_t* Ap = &Ah[(size_t)v * 64 + (fi >> 1)];
  if (res) { half2_t o2 = *Ap; y0 += (float)o2[0]; y1 += (float)o2[1]; }
  half2_t w; w[0] = (half_t)y0; w[1] = (half_t)y1;
  *Ap = w;
}

// ---------------- Global mean pool (batch is sorted, Ah fp16) ----------------
__global__ __launch_bounds__(64) void k_pool(const half2_t* __restrict__ Ah,
                                             const int* __restrict__ batch,
                                             float* __restrict__ sums) {
  const int CH = 64;
  int b0 = blockIdx.x * CH;
  int t = threadIdx.x;  // 64
  int nmax = NN - b0; if (nmax > CH) nmax = CH;
  __shared__ int bb[CH];
  bb[t] = (b0 + t < NN) ? batch[b0 + t] : -1;
  __syncthreads();
  int gfirst = bb[0], glast = bb[nmax - 1];
  if (gfirst == glast) {
    float p0 = 0.f, p1 = 0.f, q0 = 0.f, q1 = 0.f, r0 = 0.f, r1 = 0.f, u0 = 0.f, u1 = 0.f;
    int i = 0;
    for (; i + 4 <= nmax; i += 4) {
      half2_t h0 = Ah[(size_t)(b0 + i + 0) * 64 + t];
      half2_t h1 = Ah[(size_t)(b0 + i + 1) * 64 + t];
      half2_t h2 = Ah[(size_t)(b0 + i + 2) * 64 + t];
      half2_t h3 = Ah[(size_t)(b0 + i + 3) * 64 + t];
      p0 += (float)h0[0]; p1 += (float)h0[1];
      q0 += (float)h1[0]; q1 += (float)h1[1];
      r0 += (float)h2[0]; r1 += (float)h2[1];
      u0 += (float)h3[0]; u1 += (float)h3[1];
    }
    for (; i < nmax; ++i) {
      half2_t h = Ah[(size_t)(b0 + i) * 64 + t];
      p0 += (float)h[0]; p1 += (float)h[1];
    }
    atomicAdd(&sums[gfirst * DIM + 2 * t], (p0 + q0) + (r0 + u0));
    atomicAdd(&sums[gfirst * DIM + 2 * t + 1], (p1 + q1) + (r1 + u1));
  } else {
    float s0 = 0.f, s1 = 0.f;
    int cur = gfirst;
    for (int i = 0; i < nmax; i++) {
      int g = bb[i];
      if (g != cur) {
        atomicAdd(&sums[cur * DIM + 2 * t], s0);
        atomicAdd(&sums[cur * DIM + 2 * t + 1], s1);
        s0 = s1 = 0.f; cur = g;
      }
      half2_t h = Ah[(size_t)(b0 + i) * 64 + t];
      s0 += (float)h[0]; s1 += (float)h[1];
    }
    atomicAdd(&sums[cur * DIM + 2 * t], s0);
    atomicAdd(&sums[cur * DIM + 2 * t + 1], s1);
  }
}

__global__ void k_cnts(const int* __restrict__ batch, float* __restrict__ cnts) {
  int g = threadIdx.x;  // 128
  int lo = 0, hi = NN;
  while (lo < hi) { int mid = (lo + hi) >> 1; if (batch[mid] < g) lo = mid + 1; else hi = mid; }
  int a = lo;
  lo = 0; hi = NN;
  while (lo < hi) { int mid = (lo + hi) >> 1; if (batch[mid] < g + 1) lo = mid + 1; else hi = mid; }
  cnts[g] = (float)(lo - a);
}

// ---------------- Head ----------------
__global__ void k_head(const float* __restrict__ sums, const float* __restrict__ cnts,
                       const float* __restrict__ W1, const float* __restrict__ b1,
                       const float* __restrict__ W2, const float* __restrict__ b2,
                       float* __restrict__ out) {
  int g = blockIdx.x, t = threadIdx.x;  // 64
  __shared__ float p[128];
  float ic = 1.f / fmaxf(cnts[g], 1.f);
  p[t] = sums[g * DIM + t] * ic;
  p[t + 64] = sums[g * DIM + 64 + t] * ic;
  __syncthreads();
  float z = b1[t];
  #pragma unroll 8
  for (int k = 0; k < 128; k++) z += p[k] * W1[k * FCD + t];
  z = fmaxf(z, 0.f);
  float sv = z * W2[t];
  #pragma unroll
  for (int o = 1; o < 64; o <<= 1) sv += __shfl_xor(sv, o);
  if (t == 0) out[g] = 1.f / (1.f + expf(-(sv + b2[0])));
}

extern "C" void kernel_launch(void* const* d_in, const int* in_sizes, int n_in,
                              void* d_out, int out_size, void* d_ws, size_t ws_size,
                              hipStream_t stream) {
  (void)in_sizes; (void)n_in; (void)out_size; (void)ws_size;
  const float* x     = (const float*)d_in[0];
  const int*   ei    = (const int*)d_in[1];
  const int*   batch = (const int*)d_in[2];
  const float* W_in  = (const float*)d_in[3];
  const float* b_in  = (const float*)d_in[4];
  const float* g_in  = (const float*)d_in[5];
  const float* be_in = (const float*)d_in[6];
  const float* W_mid = (const float*)d_in[7];
  const float* b_mid = (const float*)d_in[8];
  const float* g_mid = (const float*)d_in[9];
  const float* be_mid= (const float*)d_in[10];
  const float* W_out = (const float*)d_in[11];
  const float* b_out = (const float*)d_in[12];
  const float* g_out = (const float*)d_in[13];
  const float* be_out= (const float*)d_in[14];
  const float* W1    = (const float*)d_in[15];
  const float* b1    = (const float*)d_in[16];
  const float* W2    = (const float*)d_in[17];
  const float* b2    = (const float*)d_in[18];
  float* out = (float*)d_out;

  // workspace layout (~95 MB)
  char* p = (char*)d_ws;
  auto alloc = [&](size_t bytes) {
    char* r = p;
    p += (bytes + 255) & ~(size_t)255;
    return r;
  };
  half_t* Ah     = (half_t*)alloc((size_t)NN * DIM * 2);  // node features (fp16, sole copy)
  half_t* Xh     = (half_t*)alloc((size_t)NN * DIM * 2);  // input x (fp16)
  half_t* Bh     = (half_t*)alloc((size_t)NN * DIM * 2);  // scaled linear output (fp16)
  half_t* Wt3    = (half_t*)alloc((size_t)3 * DIM * DIM * 2); // transposed fp16 weights
  float*  dinv   = (float*)alloc((size_t)NN * 4);
  int*    rowptr = (int*)alloc((size_t)(NN + 1) * 4);
  int*    csrc   = (int*)alloc((size_t)NE * 4);
  int*    staged = (int*)alloc((size_t)NCH * ECH * 4);
  int*    offmat = (int*)alloc((size_t)NCH * (NBK + 1) * 4);
  int*    gtot   = (int*)alloc((size_t)(NBK + 1) * 4);
  int*    gbase  = (int*)alloc((size_t)(NBK + 1) * 4);
  float*  sums   = (float*)alloc((size_t)NGRAPH * DIM * 4);
  float*  cnts   = (float*)alloc((size_t)NGRAPH * 4);

  const int* rowp = ei;        // sources
  const int* colp = ei + NE;   // targets

  hipMemsetAsync(gtot, 0, (size_t)(NBK + 1) * 4, stream);
  hipMemsetAsync(sums, 0, (size_t)NGRAPH * DIM * 4, stream);

  k_bucketA<<<NCH, 256, 0, stream>>>(rowp, colp, staged, offmat, gtot);
  k_bsum<<<1, 256, 0, stream>>>(gtot, gbase, rowptr);
  k_csrB<<<NBK, 256, 0, stream>>>(staged, offmat, gbase, rowptr, dinv, csrc);
  k_cvt<<<(NN * DIM / 4 + 255) / 256, 256, 0, stream>>>(x, Xh);
  k_wt<<<(DIM * DIM + 255) / 256, 256, 0, stream>>>(W_in,  Wt3);
  k_wt<<<(DIM * DIM + 255) / 256, 256, 0, stream>>>(W_mid, Wt3 + DIM * DIM);
  k_wt<<<(DIM * DIM + 255) / 256, 256, 0, stream>>>(W_out, Wt3 + 2 * DIM * DIM);

  int gemm_grid = (NN + 127) / 128;   // 782
  for (int l = 0; l < 8; l++) {
    const half_t* Wtl;
    const float *bl, *gl, *bel;
    if (l == 0)      { Wtl = Wt3;                 bl = b_in;  gl = g_in;  bel = be_in;  }
    else if (l == 7) { Wtl = Wt3 + 2 * DIM * DIM; bl = b_out; gl = g_out; bel = be_out; }
    else             { Wtl = Wt3 + DIM * DIM;     bl = b_mid; gl = g_mid; bel = be_mid; }
    const half_t* in = (l == 0) ? Xh : Ah;
    k_gemm<<<gemm_grid, 256, 0, stream>>>(in, (const uint4*)Wtl, dinv, Bh);
    int res = (l >= 2 && l <= 6 && (l % 2 == 0)) ? 1 : 0;
    k_agg<<<NN / 4, 256, 0, stream>>>((const half2_t*)Bh, (half2_t*)Ah,
                                      rowptr, csrc, dinv, bl, gl, bel, res);
  }

  k_pool<<<(NN + 63) / 64, 64, 0, stream>>>((const half2_t*)Ah, batch, sums);
  k_cnts<<<1, 128, 0, stream>>>(batch, cnts);
  k_head<<<NGRAPH, 64, 0, stream>>>(sums, cnts, W1, b1, W2, b2, out);
}